// Round 12
// baseline (3773.945 us; speedup 1.0000x reference)
//
#include <hip/hip_runtime.h>
#include <cstdint>
#include <cmath>

// ---------------- dims ----------------
#define NB    64
#define EMBD  300
#define EMBP  320
#define EH    512
#define DH    1024
#define GV    23262
#define GVP   23296
#define TSRC  50
#define TDEC  49
#define LDS_SCR 131072
#define LDS_TOT (131072 + 16384 + 256)
#define LDS_ENC (65536 + 16384 + 256)
#define FS    32      // ints between flags (128 B)

typedef __attribute__((ext_vector_type(8))) _Float16 f16x8;
typedef __attribute__((ext_vector_type(4))) float f32x4;

__device__ __forceinline__ float sigm(float x){ return 1.f/(1.f+expf(-x)); }

// ---- write-through (agent-scope relaxed atomic) stores, packed ----
__device__ __forceinline__ void cohS16(_Float16* p, _Float16 v){
  union { _Float16 f; unsigned short u; } c; c.f = v;
  __hip_atomic_store((unsigned short*)p, c.u, __ATOMIC_RELAXED, __HIP_MEMORY_SCOPE_AGENT);
}
__device__ __forceinline__ void cohS32(float* p, float v){
  __hip_atomic_store(p, v, __ATOMIC_RELAXED, __HIP_MEMORY_SCOPE_AGENT);
}
__device__ __forceinline__ void cohS64(void* p, unsigned long long v){
  __hip_atomic_store((unsigned long long*)p, v, __ATOMIC_RELAXED, __HIP_MEMORY_SCOPE_AGENT);
}
__device__ __forceinline__ void cohS32u(void* p, unsigned int v){
  __hip_atomic_store((unsigned int*)p, v, __ATOMIC_RELAXED, __HIP_MEMORY_SCOPE_AGENT);
}
__device__ __forceinline__ unsigned short h2u(float f){
  union { _Float16 h; unsigned short u; } c; c.h = (_Float16)f; return c.u;
}
__device__ __forceinline__ unsigned long long pk4h(float a, float b, float c, float d){
  return (unsigned long long)h2u(a) | ((unsigned long long)h2u(b)<<16)
       | ((unsigned long long)h2u(c)<<32) | ((unsigned long long)h2u(d)<<48);
}
__device__ __forceinline__ unsigned int pk2h(float a, float b){
  return (unsigned int)h2u(a) | ((unsigned int)h2u(b)<<16);
}
__device__ __forceinline__ float u2f(unsigned short u){
  union { unsigned short u; _Float16 h; } c; c.u = u; return (float)c.h;
}

// ---- flags: producers post own flag; consumers poll relaxed. No HW fence:
// all inter-step data lives in t-rotated write-once buffers (descending addr),
// so the consumer's first touch is a compulsory miss fetching post-store data.
__device__ __forceinline__ int ldF(int* p){
  return __hip_atomic_load(p, __ATOMIC_RELAXED, __HIP_MEMORY_SCOPE_AGENT);
}
__device__ __forceinline__ void stF(int* p, int v){
  __hip_atomic_store(p, v, __ATOMIC_RELAXED, __HIP_MEMORY_SCOPE_AGENT);
}
__device__ __forceinline__ void post(int* flagArr, int idx, int epoch){
  __syncthreads();   // drain this WG's write-through stores / atomics (vmcnt)
  if (threadIdx.x == 0) stF(flagArr + idx*FS, epoch);
}
__device__ __forceinline__ void flagWaitIdx(int* flagArr, int myIdx, bool active, int epoch)
{
  if (active) {
    int* p = flagArr + myIdx*FS;
    while (ldF(p) < epoch) __builtin_amdgcn_s_sleep(1);
  }
  __syncthreads();
  __atomic_signal_fence(__ATOMIC_SEQ_CST);
}

// ---- stage a [nrows][ncols] fp16 tile into LDS with XOR-16B swizzle ----
__device__ __forceinline__ void stageW(char* dst, const _Float16* __restrict__ src,
                                       int srcld, int nrows, int ncols, int tid)
{
  const int nch = ncols >> 3;
  for (int i = tid; i < nrows*nch; i += 256) {
    int row = i / nch, c = i - row*nch;
    *(f16x8*)(dst + row*ncols*2 + ((c*16) ^ ((row&7)<<4))) =
        *(const f16x8*)(src + (size_t)row*srcld + c*8);
  }
}

// 64x16 MFMA tile: acc += A[64][K](plain cached) @ B[16][K](LDS swizzled)^T
template<int K>
__device__ __forceinline__ void mm16L(f32x4 (&acc)[4],
    const _Float16* __restrict__ A, int lda,
    const char* ldsB, int rowbytes, int koffB, int lane)
{
  const int r = lane & 15, q = lane >> 4;
  const _Float16* a0 = A + r*lda + q*8;
  const char* b0 = ldsB + r*rowbytes + koffB;
  const int sw = (r & 7) << 4;
#pragma unroll
  for (int g = 0; g < K/256; ++g) {
    f16x8 av[8][4], bv[8];
#pragma unroll
    for (int s = 0; s < 8; ++s) {
      int sl = g*8 + s;
      bv[s] = *(const f16x8*)(b0 + ((sl*64 + q*16) ^ sw));
#pragma unroll
      for (int m = 0; m < 4; ++m)
        av[s][m] = *(const f16x8*)(a0 + m*16*lda + sl*32);
    }
#pragma unroll
    for (int s = 0; s < 8; ++s)
#pragma unroll
      for (int m = 0; m < 4; ++m)
        acc[m] = __builtin_amdgcn_mfma_f32_16x16x32_f16(av[s][m], bv[s], acc[m], 0, 0, 0);
  }
}

// ---------------- prep kernels ----------------
__global__ void cvt16s(const float* __restrict__ src, _Float16* __restrict__ dst,
                       int rows, int sld, int scols, int dcols)
{
  int idx = blockIdx.x*256 + threadIdx.x;
  if (idx >= rows*dcols) return;
  int c = idx % dcols, rr = idx / dcols;
  dst[idx] = (c < scols) ? (_Float16)src[(size_t)rr*sld + c] : (_Float16)0.f;
}

__global__ void cvt16t(const float* __restrict__ src, _Float16* __restrict__ dst, int n)
{
  int idx = blockIdx.x*256 + threadIdx.x;
  if (idx >= n*n) return;
  int rr = idx / n, c = idx - rr*n;
  dst[(size_t)c*n + rr] = (_Float16)src[idx];
}

__global__ void addb(const float* __restrict__ a, const float* __restrict__ b,
                     float* __restrict__ o, int n)
{
  int i = blockIdx.x*256 + threadIdx.x;
  if (i < n) o[i] = a[i] + b[i];
}

__global__ void k_embed(const int* __restrict__ src, const int* __restrict__ trg,
                        const float* __restrict__ eemb, const float* __restrict__ demb,
                        _Float16* __restrict__ x_h, _Float16* __restrict__ xrev_h,
                        _Float16* __restrict__ pe_h)
{
  int idx = blockIdx.x*256 + threadIdx.x;
  const int tot1 = TSRC*NB*EMBP;
  const int tot2 = TDEC*NB*EMBP;
  if (idx < tot1) {
    int e = idx % EMBP, rb = idx / EMBP;
    int t = rb >> 6, b = rb & 63;
    float v = 0.f;
    if (e < EMBD) v = eemb[(size_t)src[rb]*EMBD + e];
    _Float16 hv = (_Float16)v;
    x_h[idx] = hv;
    xrev_h[(size_t)((TSRC-1-t)*NB + b)*EMBP + e] = hv;
  } else if (idx < tot1 + tot2) {
    int k = idx - tot1;
    int e = k % EMBP, rb = k / EMBP;
    float v = 0.f;
    if (e < EMBD) v = demb[(size_t)trg[rb]*EMBD + e];
    pe_h[k] = (_Float16)v;
  }
}

// ---------------- big tiled GEMM (throughput path), fp16 in / f32 out ----------------
__global__ __launch_bounds__(256) void gemm128(
    const _Float16* __restrict__ A, int lda,
    const _Float16* __restrict__ W, int ldw,
    const float* __restrict__ bias,
    float* __restrict__ out, int ldo,
    int K, int mvalid, int nvalid, int rowoff)
{
  __shared__ _Float16 As[128*64];
  __shared__ _Float16 Bs[128*64];
  const int tid = threadIdx.x;
  const int m0 = blockIdx.y*128, n0 = blockIdx.x*128;
  const int w = tid >> 6, lane = tid & 63, r = lane & 15, q = lane >> 4;
  const int mw = (w >> 1)*64, nw = (w & 1)*64;
  f32x4 acc[4][4];
#pragma unroll
  for (int mi=0; mi<4; ++mi)
#pragma unroll
    for (int ni=0; ni<4; ++ni) acc[mi][ni] = 0.f;

  for (int kt = 0; kt < K; kt += 64) {
    f16x8 ra[4], rb[4];
#pragma unroll
    for (int j = 0; j < 4; ++j) {
      int c = j*256 + tid, row = c >> 3, cc = c & 7;
      ra[j] = *(const f16x8*)(A + (size_t)(m0+row)*lda + kt + cc*8);
      rb[j] = *(const f16x8*)(W + (size_t)(n0+row)*ldw + kt + cc*8);
    }
    __syncthreads();
#pragma unroll
    for (int j = 0; j < 4; ++j) {
      int c = j*256 + tid, row = c >> 3, cc = c & 7;
      int sw = cc ^ (row & 7);
      *(f16x8*)((char*)As + row*128 + (sw<<4)) = ra[j];
      *(f16x8*)((char*)Bs + row*128 + (sw<<4)) = rb[j];
    }
    __syncthreads();
#pragma unroll
    for (int kk = 0; kk < 64; kk += 32) {
      int ch = (kk >> 3) + q;
      f16x8 av[4], bv[4];
#pragma unroll
      for (int mi=0; mi<4; ++mi) {
        int row = mw + mi*16 + r;
        av[mi] = *(const f16x8*)((char*)As + row*128 + ((ch ^ (row&7))<<4));
      }
#pragma unroll
      for (int ni=0; ni<4; ++ni) {
        int row = nw + ni*16 + r;
        bv[ni] = *(const f16x8*)((char*)Bs + row*128 + ((ch ^ (row&7))<<4));
      }
#pragma unroll
      for (int mi=0; mi<4; ++mi)
#pragma unroll
        for (int ni=0; ni<4; ++ni)
          acc[mi][ni] = __builtin_amdgcn_mfma_f32_16x16x32_f16(av[mi], bv[ni], acc[mi][ni], 0,0,0);
    }
  }
#pragma unroll
  for (int mi=0; mi<4; ++mi)
#pragma unroll
    for (int ni=0; ni<4; ++ni)
#pragma unroll
      for (int e=0; e<4; ++e) {
        int mrow = m0 + mw + mi*16 + q*4 + e;
        int col  = n0 + nw + ni*16 + r;
        if (mrow < mvalid && col < nvalid)
          out[(size_t)(mrow + rowoff)*ldo + col] = acc[mi][ni][e] + bias[col];
      }
}

// same GEMM but fp16 output (eq, eo2, peproj)
__global__ __launch_bounds__(256) void gemm128h(
    const _Float16* __restrict__ A, int lda,
    const _Float16* __restrict__ W, int ldw,
    const float* __restrict__ bias,
    _Float16* __restrict__ out, int ldo,
    int K, int mvalid, int nvalid)
{
  __shared__ _Float16 As[128*64];
  __shared__ _Float16 Bs[128*64];
  const int tid = threadIdx.x;
  const int m0 = blockIdx.y*128, n0 = blockIdx.x*128;
  const int w = tid >> 6, lane = tid & 63, r = lane & 15, q = lane >> 4;
  const int mw = (w >> 1)*64, nw = (w & 1)*64;
  f32x4 acc[4][4];
#pragma unroll
  for (int mi=0; mi<4; ++mi)
#pragma unroll
    for (int ni=0; ni<4; ++ni) acc[mi][ni] = 0.f;

  for (int kt = 0; kt < K; kt += 64) {
    f16x8 ra[4], rb[4];
#pragma unroll
    for (int j = 0; j < 4; ++j) {
      int c = j*256 + tid, row = c >> 3, cc = c & 7;
      ra[j] = *(const f16x8*)(A + (size_t)(m0+row)*lda + kt + cc*8);
      rb[j] = *(const f16x8*)(W + (size_t)(n0+row)*ldw + kt + cc*8);
    }
    __syncthreads();
#pragma unroll
    for (int j = 0; j < 4; ++j) {
      int c = j*256 + tid, row = c >> 3, cc = c & 7;
      int sw = cc ^ (row & 7);
      *(f16x8*)((char*)As + row*128 + (sw<<4)) = ra[j];
      *(f16x8*)((char*)Bs + row*128 + (sw<<4)) = rb[j];
    }
    __syncthreads();
#pragma unroll
    for (int kk = 0; kk < 64; kk += 32) {
      int ch = (kk >> 3) + q;
      f16x8 av[4], bv[4];
#pragma unroll
      for (int mi=0; mi<4; ++mi) {
        int row = mw + mi*16 + r;
        av[mi] = *(const f16x8*)((char*)As + row*128 + ((ch ^ (row&7))<<4));
      }
#pragma unroll
      for (int ni=0; ni<4; ++ni) {
        int row = nw + ni*16 + r;
        bv[ni] = *(const f16x8*)((char*)Bs + row*128 + ((ch ^ (row&7))<<4));
      }
#pragma unroll
      for (int mi=0; mi<4; ++mi)
#pragma unroll
        for (int ni=0; ni<4; ++ni)
          acc[mi][ni] = __builtin_amdgcn_mfma_f32_16x16x32_f16(av[mi], bv[ni], acc[mi][ni], 0,0,0);
    }
  }
#pragma unroll
  for (int mi=0; mi<4; ++mi)
#pragma unroll
    for (int ni=0; ni<4; ++ni)
#pragma unroll
      for (int e=0; e<4; ++e) {
        int mrow = m0 + mw + mi*16 + q*4 + e;
        int col  = n0 + nw + ni*16 + r;
        if (mrow < mvalid && col < nvalid)
          out[(size_t)mrow*ldo + col] = (_Float16)(acc[mi][ni][e] + bias[col]);
      }
}

// ---------------- persistent encoder (64 WGs, 1 hop/step, rotated h) ----------------
struct EA {
  const _Float16 *whhF, *whhR;   // [2048][512]
  const float *xpF, *xpR;        // [50*64][2048] (bias folded)
  _Float16 *h;                   // [TSRC+1 slots][2 dir][64][512]; slot TSRC zeroed
  _Float16 *enc_out;             // [50][64][1024]
  _Float16 *dh0;                 // dh slot TDEC (decoder handoff)
  float *dc;                     // [64][1024]
  int *flags;                    // 64
};

__global__ __launch_bounds__(256, 1) void enc_seq(EA a)
{
  extern __shared__ char lds[];
  const int tid = threadIdx.x, w = tid >> 6, lane = tid & 63;
  const int wgid = blockIdx.x;
  const int r = lane & 15, q4 = lane >> 4;
  float (*sm4)[64][16] = (float(*)[64][16])(lds + 65536);

  const int dir = wgid >> 5, j0 = (wgid & 31) << 4;
  const _Float16* whh = dir ? a.whhR : a.whhF;
  for (int g = 0; g < 4; ++g)
    stageW(lds + g*16384, whh + (size_t)(g*EH + j0)*EH, EH, 16, 512, tid);
  __syncthreads();

  const int b = tid >> 2, jq = (tid & 3) * 4;
  float creg[4] = {0.f, 0.f, 0.f, 0.f};
  const float* xpbase = dir ? a.xpR : a.xpF;

  for (int t = 0; t < TSRC; ++t) {
    float xr[4][4];
#pragma unroll
    for (int g = 0; g < 4; ++g)
#pragma unroll
      for (int k = 0; k < 4; ++k)
        xr[g][k] = xpbase[((size_t)t*NB + b)*2048 + g*EH + j0 + jq + k];
    if (t) flagWaitIdx(a.flags, dir*32 + tid, tid < 32, t);
    const _Float16* H = a.h + ((size_t)(TSRC-t)*2 + dir)*NB*EH;
    f32x4 acc[4];
#pragma unroll
    for (int m=0;m<4;++m) acc[m] = 0.f;
    mm16L<EH>(acc, H, EH, lds + w*16384, 1024, 0, lane);
#pragma unroll
    for (int m=0;m<4;++m)
#pragma unroll
      for (int e=0;e<4;++e) sm4[w][m*16 + q4*4 + e][r] = acc[m][e];
    __syncthreads();
    _Float16* Ho = a.h + ((size_t)(TSRC-1-t)*2 + dir)*NB*EH;
    const int erow = dir ? (TSRC-1 - t) : t;
    float hv[4];
#pragma unroll
    for (int k = 0; k < 4; ++k) {
      int jj = jq + k;
      float gi = sm4[0][b][jj] + xr[0][k];
      float gf = sm4[1][b][jj] + xr[1][k];
      float gg = sm4[2][b][jj] + xr[2][k];
      float go = sm4[3][b][jj] + xr[3][k];
      float cn = sigm(gf)*creg[k] + sigm(gi)*tanhf(gg);
      creg[k] = cn;
      hv[k] = sigm(go)*tanhf(cn);
    }
    cohS64(Ho + b*EH + j0 + jq, pk4h(hv[0],hv[1],hv[2],hv[3]));
    cohS64(a.enc_out + ((size_t)erow*NB + b)*DH + dir*EH + j0 + jq, pk4h(hv[0],hv[1],hv[2],hv[3]));
    if (t == TSRC-1) {
#pragma unroll
      for (int k = 0; k < 4; ++k) {
        int j = j0 + jq + k;
        cohS16(a.dh0 + b*DH + 2*j + dir, (_Float16)hv[k]);
        cohS32(a.dc + b*DH + 2*j + dir, creg[k]);
      }
    }
    post(a.flags, wgid, t+1);
  }
}

// ---------------- score0: seed scores slot TDEC from encoder handoff ----------------
__global__ __launch_bounds__(256) void score0(
    const _Float16* __restrict__ eq, const _Float16* __restrict__ dh0,
    float* __restrict__ sc0)
{
  __shared__ float qs[1024];
  const int b = blockIdx.x, tid = threadIdx.x, w = tid >> 6, lane = tid & 63;
  if (tid < 128) {
    f16x8 v = *(const f16x8*)(dh0 + b*DH + tid*8);
#pragma unroll
    for (int k = 0; k < 8; ++k) qs[tid*8 + k] = (float)v[k];
  }
  __syncthreads();
  for (int tt = w; tt < TSRC; tt += 4) {
    const _Float16* er = eq + ((size_t)tt*NB + b)*DH + lane*16;
    const float* qq = qs + lane*16;
    f16x8 e0 = *(const f16x8*)(er);
    f16x8 e1 = *(const f16x8*)(er + 8);
    float s = 0.f;
#pragma unroll
    for (int ii=0; ii<8; ++ii) s += (float)e0[ii]*qq[ii];
#pragma unroll
    for (int ii=0; ii<8; ++ii) s += (float)e1[ii]*qq[8+ii];
#pragma unroll
    for (int o=32; o; o>>=1) s += __shfl_xor(s, o);
    if (lane == 0) sc0[tt*NB + b] = s;
  }
}

// ---------------- persistent decoder (192 WGs, 2 hops/step) ----------------
// roles: 0-63 C (ct = tanh(softmax(scores)·eo2 + wo_dh·dh), 16 cols each) |
//        64-191 D (w3c·ct + wdh·dh + pp, LSTM, next-step score partials)
struct DA {
  const _Float16 *wo;            // [1024][2048]
  const _Float16 *wdh;           // [4096][1024] dec_Whh
  const _Float16 *w3c;           // [4096][1024] dWih ct-part
  const _Float16 *eq;            // [50][64][1024] enc_out @ wi
  const _Float16 *eo2;           // [50][64][1024] enc_out @ wo_st
  const _Float16 *pp;            // [49*64][4096] pe-proj + biases (fp16)
  _Float16 *dh;                  // [TDEC+1 slots][64][1024]; slot TDEC = enc handoff
  float *dc;                     // [64][1024] (enc handoff)
  _Float16 *ct;                  // [TDEC+1 slots][64][1024]
  float *scores;                 // [TDEC+1 slots][50][64], pre-zeroed; slot TDEC by score0
  _Float16 *hdec;                // [3200][1024]
  int *flags;                    // FC 64 | FD 128
};

__global__ __launch_bounds__(256, 1) void dec_seq(DA a)
{
  extern __shared__ char lds[];
  const int tid = threadIdx.x, w = tid >> 6, lane = tid & 63;
  const int wgid = blockIdx.x;
  const int r = lane & 15, q4 = lane >> 4;
  float (*sm4)[64][16] = (float(*)[64][16])(lds + LDS_SCR);

  int* FC = a.flags;
  int* FD = FC + 64*FS;

  // ---- stage weights ----
  if (wgid < 64) {
    // C: wo_dh rows [16][1024] for cols col0..col0+15
    stageW(lds, a.wo + (size_t)(wgid*16)*2048 + 1024, 2048, 16, 1024, tid);
  } else {
    int i = wgid - 64;
    for (int g = 0; g < 4; ++g)
      stageW(lds + g*8*2048, a.wdh + (size_t)(g*1024 + i*8)*DH, DH, 8, 1024, tid);
    for (int g = 0; g < 4; ++g)
      stageW(lds + 65536 + g*8*2048, a.w3c + (size_t)(g*1024 + i*8)*DH, DH, 8, 1024, tid);
  }
  __syncthreads();

  const bool isC = (wgid < 64);
  const bool isD = (wgid >= 64);
  float dcreg[2] = {0.f, 0.f};

  for (int t = 0; t < TDEC; ++t) {
    const size_t cur = (size_t)(TDEC - t)*NB*DH;
    const size_t nxt = (size_t)(TDEC - 1 - t)*NB*DH;
    const _Float16* dhC = a.dh + cur;

    // ---- C: softmax(scores) -> ctx via eo2; + wo_dh·dh; ct = tanh ----
    if (isC) {
      if (t) flagWaitIdx(FD, tid, tid < 128, t);
      const int col0 = wgid*16;
      // stage scores(t) into LDS
      float* scb = (float*)(lds + 65536);
      const float* scg = a.scores + (size_t)(TDEC - t)*TSRC*NB;
      for (int i2 = tid; i2 < TSRC*NB; i2 += 256) scb[i2] = scg[i2];
      // MFMA wo_dh·dh (K-quarter per wave) runs while scores settle in LDS
      f32x4 acc[4];
#pragma unroll
      for (int m=0;m<4;++m) acc[m] = 0.f;
      mm16L<256>(acc, dhC + w*256, DH, lds, 2048, w*512, lane);
#pragma unroll
      for (int m=0;m<4;++m)
#pragma unroll
        for (int e=0;e<4;++e) sm4[w][m*16 + q4*4 + e][r] = acc[m][e];
      __syncthreads();
      // per-thread: b, 4 cols; softmax on the fly (redundant per quad)
      const int b = tid >> 2, cq = (tid & 3)*4;
      float mx = -1e30f;
      for (int tt = 0; tt < TSRC; ++tt) mx = fmaxf(mx, scb[tt*NB + b]);
      float ssum = 0.f;
      for (int tt = 0; tt < TSRC; ++tt) ssum += expf(scb[tt*NB + b] - mx);
      const float inv = 1.f/ssum;
      float ctx[4] = {0.f, 0.f, 0.f, 0.f};
      for (int tt = 0; tt < TSRC; ++tt) {
        float al = expf(scb[tt*NB + b] - mx);
        const _Float16* e2 = a.eo2 + ((size_t)tt*NB + b)*DH + col0 + cq;
#pragma unroll
        for (int k = 0; k < 4; ++k) ctx[k] += al*(float)e2[k];
      }
      float v[4];
#pragma unroll
      for (int k = 0; k < 4; ++k) {
        int jj = cq + k;
        float s = sm4[0][b][jj] + sm4[1][b][jj] + sm4[2][b][jj] + sm4[3][b][jj];
        v[k] = tanhf(s + ctx[k]*inv);
      }
      cohS64(a.ct + cur + b*DH + col0 + cq, pk4h(v[0],v[1],v[2],v[3]));
      post(FC, wgid, t+1);
    }

    // ---- D: gates = wdh·dh (pre-FC) + w3c·ct (post-FC) + pp; LSTM; score partials ----
    if (isD) {
      const int i = wgid - 64;
      if (t) flagWaitIdx(FD, tid, tid < 128, t);
      const int b = tid >> 2, j0 = i*8, jj2 = (tid & 3)*2;
      if (t == 0) {
        dcreg[0] = a.dc[b*DH + j0 + jj2];
        dcreg[1] = a.dc[b*DH + j0 + jj2 + 1];
      }
      const int cs = w >> 1, kh = w & 1;
      f32x4 acc[4];
#pragma unroll
      for (int m=0;m<4;++m) acc[m] = 0.f;
      mm16L<512>(acc, dhC + kh*512, DH, lds + cs*16*2048, 2048, kh*1024, lane);
      float ppv[4][2];
#pragma unroll
      for (int g = 0; g < 4; ++g)
#pragma unroll
        for (int k = 0; k < 2; ++k)
          ppv[g][k] = (float)a.pp[((size_t)t*NB + b)*4096 + g*DH + j0 + jj2 + k];
      flagWaitIdx(FC, tid, tid < 64, t+1);
      mm16L<512>(acc, a.ct + cur + kh*512, DH, lds + 65536 + cs*16*2048, 2048, kh*1024, lane);
#pragma unroll
      for (int m=0;m<4;++m)
#pragma unroll
        for (int e=0;e<4;++e) sm4[w][m*16 + q4*4 + e][r] = acc[m][e];
      __syncthreads();
      float hv[2];
#pragma unroll
      for (int k = 0; k < 2; ++k) {
        int jj = jj2 + k;
        float gi = sm4[0][b][jj]   + sm4[1][b][jj]   + ppv[0][k];
        float gf = sm4[0][b][8+jj] + sm4[1][b][8+jj] + ppv[1][k];
        float gg = sm4[2][b][jj]   + sm4[3][b][jj]   + ppv[2][k];
        float go = sm4[2][b][8+jj] + sm4[3][b][8+jj] + ppv[3][k];
        float cn = sigm(gf)*dcreg[k] + sigm(gi)*tanhf(gg);
        dcreg[k] = cn;
        hv[k] = sigm(go)*tanhf(cn);
      }
      cohS32u(a.dh + nxt + b*DH + j0 + jj2, pk2h(hv[0], hv[1]));
      cohS32u(a.hdec + ((size_t)t*NB + b)*DH + j0 + jj2, pk2h(hv[0], hv[1]));
      // next-step score partials: this thread's 2 fresh dh cols vs eq
      if (t + 1 < TDEC) {
        float* scn = a.scores + (size_t)(TDEC - 1 - t)*TSRC*NB;
        const _Float16* eqp = a.eq + (size_t)b*DH + j0 + jj2;
        for (int tt = 0; tt < TSRC; ++tt) {
          unsigned int u = *(const unsigned int*)(eqp + (size_t)tt*NB*DH);
          float p = hv[0]*u2f((unsigned short)u) + hv[1]*u2f((unsigned short)(u>>16));
          p += __shfl_xor(p, 1);
          p += __shfl_xor(p, 2);
          if ((tid & 3) == 0)
            __hip_atomic_fetch_add(scn + tt*NB + b, p, __ATOMIC_RELAXED, __HIP_MEMORY_SCOPE_AGENT);
        }
      }
      post(FD, i, t+1);
    }
  }
}

// ---------------- in-place log-softmax (online max+sum) ----------------
__global__ __launch_bounds__(256) void lsm(float* __restrict__ out)
{
  const int row = NB + blockIdx.x;
  float* p = out + (size_t)row*GV;
  const int tid = threadIdx.x;
  __shared__ float rm[4], rl[4];
  float m = -1e30f, l = 0.f;
  for (int i = tid; i < GV; i += 256) {
    float v = p[i];
    float M = fmaxf(m, v);
    l = l*expf(m - M) + expf(v - M);
    m = M;
  }
  for (int off=32; off; off>>=1) {
    float m2 = __shfl_down(m, off), l2 = __shfl_down(l, off);
    float M = fmaxf(m, m2);
    l = l*expf(m - M) + l2*expf(m2 - M);
    m = M;
  }
  if ((tid & 63) == 0) { rm[tid>>6] = m; rl[tid>>6] = l; }
  __syncthreads();
  m = rm[0]; l = rl[0];
#pragma unroll
  for (int k=1; k<4; ++k) {
    float M = fmaxf(m, rm[k]);
    l = l*expf(m - M) + rl[k]*expf(rm[k] - M);
    m = M;
  }
  float lse = m + logf(l);
  for (int i = tid; i < GV; i += 256) p[i] -= lse;
}

// ---------------- host ----------------
extern "C" void kernel_launch(void* const* d_in, const int* in_sizes, int n_in,
                              void* d_out, int out_size, void* d_ws, size_t ws_size,
                              hipStream_t stream)
{
  const int*   src  = (const int*)d_in[0];
  const int*   trg  = (const int*)d_in[1];
  const float* WihF = (const float*)d_in[2];
  const float* WhhF = (const float*)d_in[3];
  const float* bihF = (const float*)d_in[4];
  const float* bhhF = (const float*)d_in[5];
  const float* WihR = (const float*)d_in[6];
  const float* WhhR = (const float*)d_in[7];
  const float* bihR = (const float*)d_in[8];
  const float* bhhR = (const float*)d_in[9];
  const float* dWih = (const float*)d_in[10];
  const float* dWhh = (const float*)d_in[11];
  const float* dbih = (const float*)d_in[12];
  const float* dbhh = (const float*)d_in[13];
  const float* eemb = (const float*)d_in[14];
  const float* demb = (const float*)d_in[15];
  const float* wi   = (const float*)d_in[16];
  const float* wo   = (const float*)d_in[17];
  const float* genw = (const float*)d_in[18];
  const float* genb = (const float*)d_in[19];
  float* out = (float*)d_out;

  char* ws = (char*)d_ws;
  size_t off = 0;
  auto alloc = [&](size_t bytes)->char* {
    char* p = ws + off; off = (off + bytes + 255) & ~(size_t)255; return p;
  };
  _Float16* x_h    = (_Float16*)alloc((size_t)TSRC*NB*EMBP*2);
  _Float16* xrev_h = (_Float16*)alloc((size_t)TSRC*NB*EMBP*2);
  _Float16* pe_h   = (_Float16*)alloc((size_t)TDEC*NB*EMBP*2);
  _Float16* wihF_h = (_Float16*)alloc((size_t)2048*EMBP*2);
  _Float16* wihR_h = (_Float16*)alloc((size_t)2048*EMBP*2);
  _Float16* whhF_h = (_Float16*)alloc((size_t)2048*EH*2);
  _Float16* whhR_h = (_Float16*)alloc((size_t)2048*EH*2);
  _Float16* wdh_h  = (_Float16*)alloc((size_t)4096*DH*2);
  _Float16* wo_h   = (_Float16*)alloc((size_t)DH*2048*2);
  _Float16* w3c    = (_Float16*)alloc((size_t)4096*DH*2);
  _Float16* w3pe   = (_Float16*)alloc((size_t)4096*EMBP*2);
  _Float16* wiT_h  = (_Float16*)alloc((size_t)DH*DH*2);
  _Float16* genw_h = (_Float16*)alloc((size_t)GVP*DH*2);
  float* b4f   = (float*)alloc(2048*4);
  float* b4r   = (float*)alloc(2048*4);
  float* db4   = (float*)alloc(4096*4);
  float* zb    = (float*)alloc(DH*4);
  float* xp_f  = (float*)alloc((size_t)TSRC*NB*2048*4);
  float* xp_r  = (float*)alloc((size_t)TSRC*NB*2048*4);
  _Float16* peproj = (_Float16*)alloc((size_t)TDEC*NB*4096*2);
  _Float16* enc_out = (_Float16*)alloc((size_t)TSRC*NB*DH*2);
  _Float16* eq_h  = (_Float16*)alloc((size_t)TSRC*NB*DH*2);
  _Float16* eo2_h = (_Float16*)alloc((size_t)TSRC*NB*DH*2);
  _Float16* hbuf = (_Float16*)alloc((size_t)(TSRC+1)*2*NB*EH*2);
  _Float16* dh = (_Float16*)alloc((size_t)(TDEC+1)*NB*DH*2);
  float* dc = (float*)alloc((size_t)NB*DH*4);
  _Float16* ct = (_Float16*)alloc((size_t)(TDEC+1)*NB*DH*2);
  float* scores = (float*)alloc((size_t)(TDEC+1)*TSRC*NB*4);
  _Float16* hdec = (_Float16*)alloc((size_t)3200*DH*2);
  int* eflags = (int*)alloc(64*FS*4);
  int* dflags = (int*)alloc(192*FS*4);
  (void)in_sizes; (void)n_in; (void)out_size; (void)ws_size;

  // --- init / zero state (graph replays don't re-poison) ---
  hipMemsetAsync(hbuf + (size_t)TSRC*2*NB*EH, 0, (size_t)2*NB*EH*2, stream);  // h slot TSRC
  hipMemsetAsync(hdec + (size_t)3136*DH, 0, (size_t)64*DH*2, stream);
  hipMemsetAsync(genw_h + (size_t)GV*DH, 0, (size_t)(GVP-GV)*DH*2, stream);
  hipMemsetAsync(out, 0, (size_t)NB*GV*4, stream);
  hipMemsetAsync(zb, 0, DH*4, stream);
  hipMemsetAsync(scores, 0, (size_t)(TDEC+1)*TSRC*NB*4, stream);
  hipMemsetAsync(eflags, 0, 64*FS*4, stream);
  hipMemsetAsync(dflags, 0, 192*FS*4, stream);

  auto cgrid = [](size_t n){ return dim3((unsigned)((n + 255)/256)); };

  // --- weight conversion (fp16) ---
  cvt16s<<<cgrid((size_t)2048*EMBP),256,0,stream>>>(WihF, wihF_h, 2048, EMBD, EMBD, EMBP);
  cvt16s<<<cgrid((size_t)2048*EMBP),256,0,stream>>>(WihR, wihR_h, 2048, EMBD, EMBD, EMBP);
  cvt16s<<<cgrid((size_t)2048*EH),256,0,stream>>>(WhhF, whhF_h, 2048, EH, EH, EH);
  cvt16s<<<cgrid((size_t)2048*EH),256,0,stream>>>(WhhR, whhR_h, 2048, EH, EH, EH);
  cvt16s<<<cgrid((size_t)4096*DH),256,0,stream>>>(dWhh, wdh_h, 4096, DH, DH, DH);
  cvt16s<<<cgrid((size_t)DH*2048),256,0,stream>>>(wo, wo_h, DH, 2048, 2048, 2048);
  cvt16s<<<cgrid((size_t)4096*DH),256,0,stream>>>(dWih, w3c, 4096, 1324, 1024, 1024);
  cvt16s<<<cgrid((size_t)4096*EMBP),256,0,stream>>>(dWih + 1024, w3pe, 4096, 1324, 300, EMBP);
  cvt16t<<<cgrid((size_t)DH*DH),256,0,stream>>>(wi, wiT_h, DH);
  cvt16s<<<cgrid((size_t)GV*DH),256,0,stream>>>(genw, genw_h, GV, DH, DH, DH);
  addb<<<cgrid(2048),256,0,stream>>>(bihF, bhhF, b4f, 2048);
  addb<<<cgrid(2048),256,0,stream>>>(bihR, bhhR, b4r, 2048);
  addb<<<cgrid(4096),256,0,stream>>>(dbih, dbhh, db4, 4096);
  k_embed<<<cgrid((size_t)(TSRC+TDEC)*NB*EMBP),256,0,stream>>>(src, trg, eemb, demb, x_h, xrev_h, pe_h);

  // --- input projections ---
  gemm128<<<dim3(16,25),256,0,stream>>>(x_h,    EMBP, wihF_h, EMBP, b4f, xp_f, 2048, EMBP, 3200, 2048, 0);
  gemm128<<<dim3(16,25),256,0,stream>>>(xrev_h, EMBP, wihR_h, EMBP, b4r, xp_r, 2048, EMBP, 3200, 2048, 0);
  gemm128h<<<dim3(32,25),256,0,stream>>>(pe_h, EMBP, w3pe, EMBP, db4, peproj, 4096, EMBP, 3136, 4096);

  // --- encoder (persistent, 64 WGs) ---
  EA ea;
  ea.whhF = whhF_h; ea.whhR = whhR_h;
  ea.xpF = xp_f; ea.xpR = xp_r;
  ea.h = hbuf; ea.enc_out = enc_out;
  ea.dh0 = dh + (size_t)TDEC*NB*DH;
  ea.dc = dc;
  ea.flags = eflags;
  hipFuncSetAttribute((const void*)enc_seq,
                      hipFuncAttributeMaxDynamicSharedMemorySize, LDS_ENC);
  enc_seq<<<dim3(64), 256, LDS_ENC, stream>>>(ea);

  // --- eq = enc_out @ wi ; eo2 = enc_out @ wo_st ; seed scores(0) ---
  gemm128h<<<dim3(8,25),256,0,stream>>>(enc_out, DH, wiT_h, DH, zb, eq_h, DH, DH, 3200, DH);
  gemm128h<<<dim3(8,25),256,0,stream>>>(enc_out, DH, wo_h, 2048, zb, eo2_h, DH, DH, 3200, DH);
  score0<<<dim3(64),256,0,stream>>>(eq_h, dh + (size_t)TDEC*NB*DH,
                                    scores + (size_t)TDEC*TSRC*NB);

  // --- decoder (persistent, 192 WGs, 2 hops/step) ---
  DA da;
  da.wo = wo_h; da.wdh = wdh_h; da.w3c = w3c;
  da.eq = eq_h; da.eo2 = eo2_h;
  da.pp = peproj;
  da.dh = dh; da.dc = dc;
  da.ct = ct;
  da.scores = scores;
  da.hdec = hdec;
  da.flags = dflags;
  hipFuncSetAttribute((const void*)dec_seq,
                      hipFuncAttributeMaxDynamicSharedMemorySize, LDS_TOT);
  dec_seq<<<dim3(192), 256, LDS_TOT, stream>>>(da);

  // --- generator + log-softmax ---
  gemm128<<<dim3(GVP/128,25),256,0,stream>>>(hdec, DH, genw_h, DH, genb, out, GV, DH, 3136, GV, NB);
  lsm<<<3136,256,0,stream>>>(out);
}

// Round 13
// 3752.650 us; speedup vs baseline: 1.0057x; 1.0057x over previous
//
#include <hip/hip_runtime.h>
#include <cstdint>
#include <cmath>

// ---------------- dims ----------------
#define NB    64
#define EMBD  300
#define EMBP  320
#define EH    512
#define DH    1024
#define GV    23262
#define GVP   23296
#define TSRC  50
#define TDEC  49
#define TB3   3200    // TSRC*NB
#define LDS_SCR 131072
#define LDS_TOT (131072 + 16384 + 256)
#define LDS_ENC (65536 + 16384 + 256)
#define FS    32      // ints between flags (128 B)

typedef __attribute__((ext_vector_type(8))) _Float16 f16x8;
typedef __attribute__((ext_vector_type(4))) float f32x4;

__device__ __forceinline__ float sigm(float x){ return 1.f/(1.f+expf(-x)); }

// ---- write-through (agent-scope relaxed atomic) stores, packed ----
__device__ __forceinline__ void cohS16(_Float16* p, _Float16 v){
  union { _Float16 f; unsigned short u; } c; c.f = v;
  __hip_atomic_store((unsigned short*)p, c.u, __ATOMIC_RELAXED, __HIP_MEMORY_SCOPE_AGENT);
}
__device__ __forceinline__ void cohS32(float* p, float v){
  __hip_atomic_store(p, v, __ATOMIC_RELAXED, __HIP_MEMORY_SCOPE_AGENT);
}
__device__ __forceinline__ void cohS64(void* p, unsigned long long v){
  __hip_atomic_store((unsigned long long*)p, v, __ATOMIC_RELAXED, __HIP_MEMORY_SCOPE_AGENT);
}
__device__ __forceinline__ void cohS32u(void* p, unsigned int v){
  __hip_atomic_store((unsigned int*)p, v, __ATOMIC_RELAXED, __HIP_MEMORY_SCOPE_AGENT);
}
__device__ __forceinline__ unsigned short h2u(float f){
  union { _Float16 h; unsigned short u; } c; c.h = (_Float16)f; return c.u;
}
__device__ __forceinline__ unsigned long long pk4h(float a, float b, float c, float d){
  return (unsigned long long)h2u(a) | ((unsigned long long)h2u(b)<<16)
       | ((unsigned long long)h2u(c)<<32) | ((unsigned long long)h2u(d)<<48);
}
__device__ __forceinline__ unsigned int pk2h(float a, float b){
  return (unsigned int)h2u(a) | ((unsigned int)h2u(b)<<16);
}

// ---- flags: producers post own flag; consumers poll relaxed. No HW fence:
// all inter-step data lives in t-rotated write-once buffers (descending addr),
// so the consumer's first touch is a compulsory miss fetching post-store data.
__device__ __forceinline__ int ldF(int* p){
  return __hip_atomic_load(p, __ATOMIC_RELAXED, __HIP_MEMORY_SCOPE_AGENT);
}
__device__ __forceinline__ void stF(int* p, int v){
  __hip_atomic_store(p, v, __ATOMIC_RELAXED, __HIP_MEMORY_SCOPE_AGENT);
}
__device__ __forceinline__ void post(int* flagArr, int idx, int epoch){
  __syncthreads();   // drain this WG's write-through stores / atomics (vmcnt)
  if (threadIdx.x == 0) stF(flagArr + idx*FS, epoch);
}
__device__ __forceinline__ void flagWaitIdx(int* flagArr, int myIdx, bool active, int epoch)
{
  if (active) {
    int* p = flagArr + myIdx*FS;
    while (ldF(p) < epoch) __builtin_amdgcn_s_sleep(1);
  }
  __syncthreads();
  __atomic_signal_fence(__ATOMIC_SEQ_CST);
}

// ---- stage a [nrows][ncols] fp16 tile into LDS with XOR-16B swizzle ----
__device__ __forceinline__ void stageW(char* dst, const _Float16* __restrict__ src,
                                       int srcld, int nrows, int ncols, int tid)
{
  const int nch = ncols >> 3;
  for (int i = tid; i < nrows*nch; i += 256) {
    int row = i / nch, c = i - row*nch;
    *(f16x8*)(dst + row*ncols*2 + ((c*16) ^ ((row&7)<<4))) =
        *(const f16x8*)(src + (size_t)row*srcld + c*8);
  }
}

// 64x16 MFMA tile: acc += A[64][K](plain cached) @ B[16][K](LDS swizzled)^T
template<int K>
__device__ __forceinline__ void mm16L(f32x4 (&acc)[4],
    const _Float16* __restrict__ A, int lda,
    const char* ldsB, int rowbytes, int koffB, int lane)
{
  const int r = lane & 15, q = lane >> 4;
  const _Float16* a0 = A + r*lda + q*8;
  const char* b0 = ldsB + r*rowbytes + koffB;
  const int sw = (r & 7) << 4;
#pragma unroll
  for (int g = 0; g < K/256; ++g) {
    f16x8 av[8][4], bv[8];
#pragma unroll
    for (int s = 0; s < 8; ++s) {
      int sl = g*8 + s;
      bv[s] = *(const f16x8*)(b0 + ((sl*64 + q*16) ^ sw));
#pragma unroll
      for (int m = 0; m < 4; ++m)
        av[s][m] = *(const f16x8*)(a0 + m*16*lda + sl*32);
    }
#pragma unroll
    for (int s = 0; s < 8; ++s)
#pragma unroll
      for (int m = 0; m < 4; ++m)
        acc[m] = __builtin_amdgcn_mfma_f32_16x16x32_f16(av[s][m], bv[s], acc[m], 0, 0, 0);
  }
}

// ---------------- prep kernels ----------------
__global__ void cvt16s(const float* __restrict__ src, _Float16* __restrict__ dst,
                       int rows, int sld, int scols, int dcols)
{
  int idx = blockIdx.x*256 + threadIdx.x;
  if (idx >= rows*dcols) return;
  int c = idx % dcols, rr = idx / dcols;
  dst[idx] = (c < scols) ? (_Float16)src[(size_t)rr*sld + c] : (_Float16)0.f;
}

__global__ void cvt16t(const float* __restrict__ src, _Float16* __restrict__ dst, int n)
{
  int idx = blockIdx.x*256 + threadIdx.x;
  if (idx >= n*n) return;
  int rr = idx / n, c = idx - rr*n;
  dst[(size_t)c*n + rr] = (_Float16)src[idx];
}

__global__ void addb(const float* __restrict__ a, const float* __restrict__ b,
                     float* __restrict__ o, int n)
{
  int i = blockIdx.x*256 + threadIdx.x;
  if (i < n) o[i] = a[i] + b[i];
}

__global__ void k_embed(const int* __restrict__ src, const int* __restrict__ trg,
                        const float* __restrict__ eemb, const float* __restrict__ demb,
                        _Float16* __restrict__ x_h, _Float16* __restrict__ xrev_h,
                        _Float16* __restrict__ pe_h)
{
  int idx = blockIdx.x*256 + threadIdx.x;
  const int tot1 = TSRC*NB*EMBP;
  const int tot2 = TDEC*NB*EMBP;
  if (idx < tot1) {
    int e = idx % EMBP, rb = idx / EMBP;
    int t = rb >> 6, b = rb & 63;
    float v = 0.f;
    if (e < EMBD) v = eemb[(size_t)src[rb]*EMBD + e];
    _Float16 hv = (_Float16)v;
    x_h[idx] = hv;
    xrev_h[(size_t)((TSRC-1-t)*NB + b)*EMBP + e] = hv;
  } else if (idx < tot1 + tot2) {
    int k = idx - tot1;
    int e = k % EMBP, rb = k / EMBP;
    float v = 0.f;
    if (e < EMBD) v = demb[(size_t)trg[rb]*EMBD + e];
    pe_h[k] = (_Float16)v;
  }
}

// ---------------- big tiled GEMM (throughput path), fp16 in / f32 out ----------------
__global__ __launch_bounds__(256) void gemm128(
    const _Float16* __restrict__ A, int lda,
    const _Float16* __restrict__ W, int ldw,
    const float* __restrict__ bias,
    float* __restrict__ out, int ldo,
    int K, int mvalid, int nvalid, int rowoff)
{
  __shared__ _Float16 As[128*64];
  __shared__ _Float16 Bs[128*64];
  const int tid = threadIdx.x;
  const int m0 = blockIdx.y*128, n0 = blockIdx.x*128;
  const int w = tid >> 6, lane = tid & 63, r = lane & 15, q = lane >> 4;
  const int mw = (w >> 1)*64, nw = (w & 1)*64;
  f32x4 acc[4][4];
#pragma unroll
  for (int mi=0; mi<4; ++mi)
#pragma unroll
    for (int ni=0; ni<4; ++ni) acc[mi][ni] = 0.f;

  for (int kt = 0; kt < K; kt += 64) {
    f16x8 ra[4], rb[4];
#pragma unroll
    for (int j = 0; j < 4; ++j) {
      int c = j*256 + tid, row = c >> 3, cc = c & 7;
      ra[j] = *(const f16x8*)(A + (size_t)(m0+row)*lda + kt + cc*8);
      rb[j] = *(const f16x8*)(W + (size_t)(n0+row)*ldw + kt + cc*8);
    }
    __syncthreads();
#pragma unroll
    for (int j = 0; j < 4; ++j) {
      int c = j*256 + tid, row = c >> 3, cc = c & 7;
      int sw = cc ^ (row & 7);
      *(f16x8*)((char*)As + row*128 + (sw<<4)) = ra[j];
      *(f16x8*)((char*)Bs + row*128 + (sw<<4)) = rb[j];
    }
    __syncthreads();
#pragma unroll
    for (int kk = 0; kk < 64; kk += 32) {
      int ch = (kk >> 3) + q;
      f16x8 av[4], bv[4];
#pragma unroll
      for (int mi=0; mi<4; ++mi) {
        int row = mw + mi*16 + r;
        av[mi] = *(const f16x8*)((char*)As + row*128 + ((ch ^ (row&7))<<4));
      }
#pragma unroll
      for (int ni=0; ni<4; ++ni) {
        int row = nw + ni*16 + r;
        bv[ni] = *(const f16x8*)((char*)Bs + row*128 + ((ch ^ (row&7))<<4));
      }
#pragma unroll
      for (int mi=0; mi<4; ++mi)
#pragma unroll
        for (int ni=0; ni<4; ++ni)
          acc[mi][ni] = __builtin_amdgcn_mfma_f32_16x16x32_f16(av[mi], bv[ni], acc[mi][ni], 0,0,0);
    }
  }
#pragma unroll
  for (int mi=0; mi<4; ++mi)
#pragma unroll
    for (int ni=0; ni<4; ++ni)
#pragma unroll
      for (int e=0; e<4; ++e) {
        int mrow = m0 + mw + mi*16 + q*4 + e;
        int col  = n0 + nw + ni*16 + r;
        if (mrow < mvalid && col < nvalid)
          out[(size_t)(mrow + rowoff)*ldo + col] = acc[mi][ni][e] + bias[col];
      }
}

// same GEMM but fp16 output (eqT, eo2T, peproj)
__global__ __launch_bounds__(256) void gemm128h(
    const _Float16* __restrict__ A, int lda,
    const _Float16* __restrict__ W, int ldw,
    const float* __restrict__ bias,
    _Float16* __restrict__ out, int ldo,
    int K, int mvalid, int nvalid)
{
  __shared__ _Float16 As[128*64];
  __shared__ _Float16 Bs[128*64];
  const int tid = threadIdx.x;
  const int m0 = blockIdx.y*128, n0 = blockIdx.x*128;
  const int w = tid >> 6, lane = tid & 63, r = lane & 15, q = lane >> 4;
  const int mw = (w >> 1)*64, nw = (w & 1)*64;
  f32x4 acc[4][4];
#pragma unroll
  for (int mi=0; mi<4; ++mi)
#pragma unroll
    for (int ni=0; ni<4; ++ni) acc[mi][ni] = 0.f;

  for (int kt = 0; kt < K; kt += 64) {
    f16x8 ra[4], rb[4];
#pragma unroll
    for (int j = 0; j < 4; ++j) {
      int c = j*256 + tid, row = c >> 3, cc = c & 7;
      ra[j] = *(const f16x8*)(A + (size_t)(m0+row)*lda + kt + cc*8);
      rb[j] = *(const f16x8*)(W + (size_t)(n0+row)*ldw + kt + cc*8);
    }
    __syncthreads();
#pragma unroll
    for (int j = 0; j < 4; ++j) {
      int c = j*256 + tid, row = c >> 3, cc = c & 7;
      int sw = cc ^ (row & 7);
      *(f16x8*)((char*)As + row*128 + (sw<<4)) = ra[j];
      *(f16x8*)((char*)Bs + row*128 + (sw<<4)) = rb[j];
    }
    __syncthreads();
#pragma unroll
    for (int kk = 0; kk < 64; kk += 32) {
      int ch = (kk >> 3) + q;
      f16x8 av[4], bv[4];
#pragma unroll
      for (int mi=0; mi<4; ++mi) {
        int row = mw + mi*16 + r;
        av[mi] = *(const f16x8*)((char*)As + row*128 + ((ch ^ (row&7))<<4));
      }
#pragma unroll
      for (int ni=0; ni<4; ++ni) {
        int row = nw + ni*16 + r;
        bv[ni] = *(const f16x8*)((char*)Bs + row*128 + ((ch ^ (row&7))<<4));
      }
#pragma unroll
      for (int mi=0; mi<4; ++mi)
#pragma unroll
        for (int ni=0; ni<4; ++ni)
          acc[mi][ni] = __builtin_amdgcn_mfma_f32_16x16x32_f16(av[mi], bv[ni], acc[mi][ni], 0,0,0);
    }
  }
#pragma unroll
  for (int mi=0; mi<4; ++mi)
#pragma unroll
    for (int ni=0; ni<4; ++ni)
#pragma unroll
      for (int e=0; e<4; ++e) {
        int mrow = m0 + mw + mi*16 + q*4 + e;
        int col  = n0 + nw + ni*16 + r;
        if (mrow < mvalid && col < nvalid)
          out[(size_t)mrow*ldo + col] = (_Float16)(acc[mi][ni][e] + bias[col]);
      }
}

// ---------------- persistent encoder (64 WGs, 1 hop/step, rotated h) ----------------
struct EA {
  const _Float16 *whhF, *whhR;   // [2048][512]
  const float *xpF, *xpR;        // [50*64][2048] (bias folded)
  _Float16 *h;                   // [TSRC+1 slots][2 dir][64][512]; slot TSRC zeroed
  _Float16 *enc_out;             // [50][64][1024]
  _Float16 *dh0;                 // dh slot TDEC (decoder handoff)
  float *dc;                     // [64][1024]
  int *flags;                    // 64
};

__global__ __launch_bounds__(256, 1) void enc_seq(EA a)
{
  extern __shared__ char lds[];
  const int tid = threadIdx.x, w = tid >> 6, lane = tid & 63;
  const int wgid = blockIdx.x;
  const int r = lane & 15, q4 = lane >> 4;
  float (*sm4)[64][16] = (float(*)[64][16])(lds + 65536);

  const int dir = wgid >> 5, j0 = (wgid & 31) << 4;
  const _Float16* whh = dir ? a.whhR : a.whhF;
  for (int g = 0; g < 4; ++g)
    stageW(lds + g*16384, whh + (size_t)(g*EH + j0)*EH, EH, 16, 512, tid);
  __syncthreads();

  const int b = tid >> 2, jq = (tid & 3) * 4;
  float creg[4] = {0.f, 0.f, 0.f, 0.f};
  const float* xpbase = dir ? a.xpR : a.xpF;

  for (int t = 0; t < TSRC; ++t) {
    float xr[4][4];
#pragma unroll
    for (int g = 0; g < 4; ++g)
#pragma unroll
      for (int k = 0; k < 4; ++k)
        xr[g][k] = xpbase[((size_t)t*NB + b)*2048 + g*EH + j0 + jq + k];
    if (t) flagWaitIdx(a.flags, dir*32 + tid, tid < 32, t);
    const _Float16* H = a.h + ((size_t)(TSRC-t)*2 + dir)*NB*EH;
    f32x4 acc[4];
#pragma unroll
    for (int m=0;m<4;++m) acc[m] = 0.f;
    mm16L<EH>(acc, H, EH, lds + w*16384, 1024, 0, lane);
#pragma unroll
    for (int m=0;m<4;++m)
#pragma unroll
      for (int e=0;e<4;++e) sm4[w][m*16 + q4*4 + e][r] = acc[m][e];
    __syncthreads();
    _Float16* Ho = a.h + ((size_t)(TSRC-1-t)*2 + dir)*NB*EH;
    const int erow = dir ? (TSRC-1 - t) : t;
    float hv[4];
#pragma unroll
    for (int k = 0; k < 4; ++k) {
      int jj = jq + k;
      float gi = sm4[0][b][jj] + xr[0][k];
      float gf = sm4[1][b][jj] + xr[1][k];
      float gg = sm4[2][b][jj] + xr[2][k];
      float go = sm4[3][b][jj] + xr[3][k];
      float cn = sigm(gf)*creg[k] + sigm(gi)*tanhf(gg);
      creg[k] = cn;
      hv[k] = sigm(go)*tanhf(cn);
    }
    cohS64(Ho + b*EH + j0 + jq, pk4h(hv[0],hv[1],hv[2],hv[3]));
    cohS64(a.enc_out + ((size_t)erow*NB + b)*DH + dir*EH + j0 + jq, pk4h(hv[0],hv[1],hv[2],hv[3]));
    if (t == TSRC-1) {
#pragma unroll
      for (int k = 0; k < 4; ++k) {
        int j = j0 + jq + k;
        cohS16(a.dh0 + b*DH + 2*j + dir, (_Float16)hv[k]);
        cohS32(a.dc + b*DH + 2*j + dir, creg[k]);
      }
    }
    post(a.flags, wgid, t+1);
  }
}

// ---------------- score0T: seed scores slot TDEC from encoder handoff (eqT layout) ----------------
__global__ __launch_bounds__(256) void score0T(
    const _Float16* __restrict__ eqT, const _Float16* __restrict__ dh0,
    float* __restrict__ sc0)
{
  __shared__ float red[4][64];
  const int tt = blockIdx.x, tid = threadIdx.x, b = tid & 63, seg = tid >> 6;
  float s = 0.f;
  for (int k = seg*256; k < (seg+1)*256; ++k)
    s += (float)eqT[(size_t)k*TB3 + tt*NB + b] * (float)dh0[b*DH + k];
  red[seg][b] = s;
  __syncthreads();
  if (tid < 64)
    sc0[tt*NB + tid] = red[0][tid] + red[1][tid] + red[2][tid] + red[3][tid];
}

// ---------------- persistent decoder (192 WGs, 2 hops/step) ----------------
// roles: 0-63 C (ct = tanh(softmax(scores)·eo2 + wo_dh·dh), 16 cols each) |
//        64-191 D (w3c·ct + wdh·dh + pp, LSTM, next-step score partials)
// eqT/eo2T are [DH][3200] (col-major over (tt,b)) -> lane-over-b coalesced,
// per-WG slices are small and L2-resident (the r12 FETCH-explosion fix).
struct DA {
  const _Float16 *wo;            // [1024][2048]
  const _Float16 *wdh;           // [4096][1024] dec_Whh
  const _Float16 *w3c;           // [4096][1024] dWih ct-part
  const _Float16 *eqT;           // [1024][3200]  (enc_out @ wi)^T
  const _Float16 *eo2T;          // [1024][3200]  (enc_out @ wo_st)^T
  const _Float16 *pp;            // [49*64][4096] pe-proj + biases (fp16)
  _Float16 *dh;                  // [TDEC+1 slots][64][1024]; slot TDEC = enc handoff
  float *dc;                     // [64][1024] (enc handoff)
  _Float16 *ct;                  // [TDEC+1 slots][64][1024]
  float *scores;                 // [TDEC+1 slots][50][64], pre-zeroed; slot TDEC by score0T
  _Float16 *hdec;                // [3200][1024]
  int *flags;                    // FC 64 | FD 128
};

__global__ __launch_bounds__(256, 1) void dec_seq(DA a)
{
  extern __shared__ char lds[];
  const int tid = threadIdx.x, w = tid >> 6, lane = tid & 63;
  const int wgid = blockIdx.x;
  const int r = lane & 15, q4 = lane >> 4;
  float (*sm4)[64][16] = (float(*)[64][16])(lds + LDS_SCR);

  int* FC = a.flags;
  int* FD = FC + 64*FS;

  // ---- stage weights ----
  if (wgid < 64) {
    stageW(lds, a.wo + (size_t)(wgid*16)*2048 + 1024, 2048, 16, 1024, tid);
  } else {
    int i = wgid - 64;
    for (int g = 0; g < 4; ++g)
      stageW(lds + g*8*2048, a.wdh + (size_t)(g*1024 + i*8)*DH, DH, 8, 1024, tid);
    for (int g = 0; g < 4; ++g)
      stageW(lds + 65536 + g*8*2048, a.w3c + (size_t)(g*1024 + i*8)*DH, DH, 8, 1024, tid);
  }
  __syncthreads();

  const bool isC = (wgid < 64);
  const bool isD = (wgid >= 64);
  float dcreg[2] = {0.f, 0.f};

  for (int t = 0; t < TDEC; ++t) {
    const size_t cur = (size_t)(TDEC - t)*NB*DH;
    const size_t nxt = (size_t)(TDEC - 1 - t)*NB*DH;
    const _Float16* dhC = a.dh + cur;

    // ---- C: softmax(scores) -> ctx via eo2T; + wo_dh·dh; ct = tanh ----
    if (isC) {
      if (t) flagWaitIdx(FD, tid, tid < 128, t);
      const int col0 = wgid*16;
      float* scb = (float*)(lds + 65536);
      const float* scg = a.scores + (size_t)(TDEC - t)*TSRC*NB;
      for (int i2 = tid; i2 < TSRC*NB; i2 += 256) scb[i2] = scg[i2];
      f32x4 acc[4];
#pragma unroll
      for (int m=0;m<4;++m) acc[m] = 0.f;
      mm16L<256>(acc, dhC + w*256, DH, lds, 2048, w*512, lane);
#pragma unroll
      for (int m=0;m<4;++m)
#pragma unroll
        for (int e=0;e<4;++e) sm4[w][m*16 + q4*4 + e][r] = acc[m][e];
      __syncthreads();
      const int b = tid >> 2, cq = (tid & 3)*4;
      float mx = -1e30f;
      for (int tt = 0; tt < TSRC; ++tt) mx = fmaxf(mx, scb[tt*NB + b]);
      float ssum = 0.f;
      for (int tt = 0; tt < TSRC; ++tt) ssum += expf(scb[tt*NB + b] - mx);
      const float inv = 1.f/ssum;
      float ctx[4] = {0.f, 0.f, 0.f, 0.f};
      for (int tt = 0; tt < TSRC; ++tt) {
        float al = expf(scb[tt*NB + b] - mx);
#pragma unroll
        for (int k = 0; k < 4; ++k)
          ctx[k] += al*(float)a.eo2T[(size_t)(col0 + cq + k)*TB3 + tt*NB + b];
      }
      float v[4];
#pragma unroll
      for (int k = 0; k < 4; ++k) {
        int jj = cq + k;
        float s = sm4[0][b][jj] + sm4[1][b][jj] + sm4[2][b][jj] + sm4[3][b][jj];
        v[k] = tanhf(s + ctx[k]*inv);
      }
      cohS64(a.ct + cur + b*DH + col0 + cq, pk4h(v[0],v[1],v[2],v[3]));
      post(FC, wgid, t+1);
    }

    // ---- D: gates = wdh·dh (pre-FC) + w3c·ct (post-FC) + pp; LSTM; score partials ----
    if (isD) {
      const int i = wgid - 64;
      if (t) flagWaitIdx(FD, tid, tid < 128, t);
      const int b = tid >> 2, j0 = i*8, jj2 = (tid & 3)*2;
      if (t == 0) {
        dcreg[0] = a.dc[b*DH + j0 + jj2];
        dcreg[1] = a.dc[b*DH + j0 + jj2 + 1];
      }
      const int cs = w >> 1, kh = w & 1;
      f32x4 acc[4];
#pragma unroll
      for (int m=0;m<4;++m) acc[m] = 0.f;
      mm16L<512>(acc, dhC + kh*512, DH, lds + cs*16*2048, 2048, kh*1024, lane);
      float ppv[4][2];
#pragma unroll
      for (int g = 0; g < 4; ++g)
#pragma unroll
        for (int k = 0; k < 2; ++k)
          ppv[g][k] = (float)a.pp[((size_t)t*NB + b)*4096 + g*DH + j0 + jj2 + k];
      flagWaitIdx(FC, tid, tid < 64, t+1);
      mm16L<512>(acc, a.ct + cur + kh*512, DH, lds + 65536 + cs*16*2048, 2048, kh*1024, lane);
#pragma unroll
      for (int m=0;m<4;++m)
#pragma unroll
        for (int e=0;e<4;++e) sm4[w][m*16 + q4*4 + e][r] = acc[m][e];
      __syncthreads();
      float hv[2];
#pragma unroll
      for (int k = 0; k < 2; ++k) {
        int jj = jj2 + k;
        float gi = sm4[0][b][jj]   + sm4[1][b][jj]   + ppv[0][k];
        float gf = sm4[0][b][8+jj] + sm4[1][b][8+jj] + ppv[1][k];
        float gg = sm4[2][b][jj]   + sm4[3][b][jj]   + ppv[2][k];
        float go = sm4[2][b][8+jj] + sm4[3][b][8+jj] + ppv[3][k];
        float cn = sigm(gf)*dcreg[k] + sigm(gi)*tanhf(gg);
        dcreg[k] = cn;
        hv[k] = sigm(go)*tanhf(cn);
      }
      cohS32u(a.dh + nxt + b*DH + j0 + jj2, pk2h(hv[0], hv[1]));
      cohS32u(a.hdec + ((size_t)t*NB + b)*DH + j0 + jj2, pk2h(hv[0], hv[1]));
      // next-step score partials: eqT rows (j0+jj2, j0+jj2+1), lane-over-b coalesced
      if (t + 1 < TDEC) {
        float* scn = a.scores + (size_t)(TDEC - 1 - t)*TSRC*NB;
        const _Float16* r0 = a.eqT + (size_t)(j0 + jj2)*TB3 + b;
        const _Float16* r1 = a.eqT + (size_t)(j0 + jj2 + 1)*TB3 + b;
        for (int tt = 0; tt < TSRC; ++tt) {
          float p = hv[0]*(float)r0[tt*NB] + hv[1]*(float)r1[tt*NB];
          p += __shfl_xor(p, 1);
          p += __shfl_xor(p, 2);
          if ((tid & 3) == 0)
            __hip_atomic_fetch_add(scn + tt*NB + b, p, __ATOMIC_RELAXED, __HIP_MEMORY_SCOPE_AGENT);
        }
      }
      post(FD, i, t+1);
    }
  }
}

// ---------------- in-place log-softmax (online max+sum) ----------------
__global__ __launch_bounds__(256) void lsm(float* __restrict__ out)
{
  const int row = NB + blockIdx.x;
  float* p = out + (size_t)row*GV;
  const int tid = threadIdx.x;
  __shared__ float rm[4], rl[4];
  float m = -1e30f, l = 0.f;
  for (int i = tid; i < GV; i += 256) {
    float v = p[i];
    float M = fmaxf(m, v);
    l = l*expf(m - M) + expf(v - M);
    m = M;
  }
  for (int off=32; off; off>>=1) {
    float m2 = __shfl_down(m, off), l2 = __shfl_down(l, off);
    float M = fmaxf(m, m2);
    l = l*expf(m - M) + l2*expf(m2 - M);
    m = M;
  }
  if ((tid & 63) == 0) { rm[tid>>6] = m; rl[tid>>6] = l; }
  __syncthreads();
  m = rm[0]; l = rl[0];
#pragma unroll
  for (int k=1; k<4; ++k) {
    float M = fmaxf(m, rm[k]);
    l = l*expf(m - M) + rl[k]*expf(rm[k] - M);
    m = M;
  }
  float lse = m + logf(l);
  for (int i = tid; i < GV; i += 256) p[i] -= lse;
}

// ---------------- host ----------------
extern "C" void kernel_launch(void* const* d_in, const int* in_sizes, int n_in,
                              void* d_out, int out_size, void* d_ws, size_t ws_size,
                              hipStream_t stream)
{
  const int*   src  = (const int*)d_in[0];
  const int*   trg  = (const int*)d_in[1];
  const float* WihF = (const float*)d_in[2];
  const float* WhhF = (const float*)d_in[3];
  const float* bihF = (const float*)d_in[4];
  const float* bhhF = (const float*)d_in[5];
  const float* WihR = (const float*)d_in[6];
  const float* WhhR = (const float*)d_in[7];
  const float* bihR = (const float*)d_in[8];
  const float* bhhR = (const float*)d_in[9];
  const float* dWih = (const float*)d_in[10];
  const float* dWhh = (const float*)d_in[11];
  const float* dbih = (const float*)d_in[12];
  const float* dbhh = (const float*)d_in[13];
  const float* eemb = (const float*)d_in[14];
  const float* demb = (const float*)d_in[15];
  const float* wi   = (const float*)d_in[16];
  const float* wo   = (const float*)d_in[17];
  const float* genw = (const float*)d_in[18];
  const float* genb = (const float*)d_in[19];
  float* out = (float*)d_out;

  char* ws = (char*)d_ws;
  size_t off = 0;
  auto alloc = [&](size_t bytes)->char* {
    char* p = ws + off; off = (off + bytes + 255) & ~(size_t)255; return p;
  };
  _Float16* x_h    = (_Float16*)alloc((size_t)TSRC*NB*EMBP*2);
  _Float16* xrev_h = (_Float16*)alloc((size_t)TSRC*NB*EMBP*2);
  _Float16* pe_h   = (_Float16*)alloc((size_t)TDEC*NB*EMBP*2);
  _Float16* wihF_h = (_Float16*)alloc((size_t)2048*EMBP*2);
  _Float16* wihR_h = (_Float16*)alloc((size_t)2048*EMBP*2);
  _Float16* whhF_h = (_Float16*)alloc((size_t)2048*EH*2);
  _Float16* whhR_h = (_Float16*)alloc((size_t)2048*EH*2);
  _Float16* wdh_h  = (_Float16*)alloc((size_t)4096*DH*2);
  _Float16* wo_h   = (_Float16*)alloc((size_t)DH*2048*2);
  _Float16* w3c    = (_Float16*)alloc((size_t)4096*DH*2);
  _Float16* w3pe   = (_Float16*)alloc((size_t)4096*EMBP*2);
  _Float16* wiT_h  = (_Float16*)alloc((size_t)DH*DH*2);
  _Float16* genw_h = (_Float16*)alloc((size_t)GVP*DH*2);
  float* b4f   = (float*)alloc(2048*4);
  float* b4r   = (float*)alloc(2048*4);
  float* db4   = (float*)alloc(4096*4);
  float* zb    = (float*)alloc(TB3*4);
  float* xp_f  = (float*)alloc((size_t)TSRC*NB*2048*4);
  float* xp_r  = (float*)alloc((size_t)TSRC*NB*2048*4);
  _Float16* peproj = (_Float16*)alloc((size_t)TDEC*NB*4096*2);
  _Float16* enc_out = (_Float16*)alloc((size_t)TSRC*NB*DH*2);
  _Float16* eqT_h  = (_Float16*)alloc((size_t)DH*TB3*2);
  _Float16* eo2T_h = (_Float16*)alloc((size_t)DH*TB3*2);
  _Float16* hbuf = (_Float16*)alloc((size_t)(TSRC+1)*2*NB*EH*2);
  _Float16* dh = (_Float16*)alloc((size_t)(TDEC+1)*NB*DH*2);
  float* dc = (float*)alloc((size_t)NB*DH*4);
  _Float16* ct = (_Float16*)alloc((size_t)(TDEC+1)*NB*DH*2);
  float* scores = (float*)alloc((size_t)(TDEC+1)*TSRC*NB*4);
  _Float16* hdec = (_Float16*)alloc((size_t)3200*DH*2);
  int* eflags = (int*)alloc(64*FS*4);
  int* dflags = (int*)alloc(192*FS*4);
  (void)in_sizes; (void)n_in; (void)out_size; (void)ws_size;

  // --- init / zero state (graph replays don't re-poison) ---
  hipMemsetAsync(hbuf + (size_t)TSRC*2*NB*EH, 0, (size_t)2*NB*EH*2, stream);  // h slot TSRC
  hipMemsetAsync(hdec + (size_t)3136*DH, 0, (size_t)64*DH*2, stream);
  hipMemsetAsync(genw_h + (size_t)GV*DH, 0, (size_t)(GVP-GV)*DH*2, stream);
  hipMemsetAsync(out, 0, (size_t)NB*GV*4, stream);
  hipMemsetAsync(zb, 0, TB3*4, stream);
  hipMemsetAsync(scores, 0, (size_t)(TDEC+1)*TSRC*NB*4, stream);
  hipMemsetAsync(eflags, 0, 64*FS*4, stream);
  hipMemsetAsync(dflags, 0, 192*FS*4, stream);

  auto cgrid = [](size_t n){ return dim3((unsigned)((n + 255)/256)); };

  // --- weight conversion (fp16) ---
  cvt16s<<<cgrid((size_t)2048*EMBP),256,0,stream>>>(WihF, wihF_h, 2048, EMBD, EMBD, EMBP);
  cvt16s<<<cgrid((size_t)2048*EMBP),256,0,stream>>>(WihR, wihR_h, 2048, EMBD, EMBD, EMBP);
  cvt16s<<<cgrid((size_t)2048*EH),256,0,stream>>>(WhhF, whhF_h, 2048, EH, EH, EH);
  cvt16s<<<cgrid((size_t)2048*EH),256,0,stream>>>(WhhR, whhR_h, 2048, EH, EH, EH);
  cvt16s<<<cgrid((size_t)4096*DH),256,0,stream>>>(dWhh, wdh_h, 4096, DH, DH, DH);
  cvt16s<<<cgrid((size_t)DH*2048),256,0,stream>>>(wo, wo_h, DH, 2048, 2048, 2048);
  cvt16s<<<cgrid((size_t)4096*DH),256,0,stream>>>(dWih, w3c, 4096, 1324, 1024, 1024);
  cvt16s<<<cgrid((size_t)4096*EMBP),256,0,stream>>>(dWih + 1024, w3pe, 4096, 1324, 300, EMBP);
  cvt16t<<<cgrid((size_t)DH*DH),256,0,stream>>>(wi, wiT_h, DH);
  cvt16s<<<cgrid((size_t)GV*DH),256,0,stream>>>(genw, genw_h, GV, DH, DH, DH);
  addb<<<cgrid(2048),256,0,stream>>>(bihF, bhhF, b4f, 2048);
  addb<<<cgrid(2048),256,0,stream>>>(bihR, bhhR, b4r, 2048);
  addb<<<cgrid(4096),256,0,stream>>>(dbih, dbhh, db4, 4096);
  k_embed<<<cgrid((size_t)(TSRC+TDEC)*NB*EMBP),256,0,stream>>>(src, trg, eemb, demb, x_h, xrev_h, pe_h);

  // --- input projections ---
  gemm128<<<dim3(16,25),256,0,stream>>>(x_h,    EMBP, wihF_h, EMBP, b4f, xp_f, 2048, EMBP, 3200, 2048, 0);
  gemm128<<<dim3(16,25),256,0,stream>>>(xrev_h, EMBP, wihR_h, EMBP, b4r, xp_r, 2048, EMBP, 3200, 2048, 0);
  gemm128h<<<dim3(32,25),256,0,stream>>>(pe_h, EMBP, w3pe, EMBP, db4, peproj, 4096, EMBP, 3136, 4096);

  // --- encoder (persistent, 64 WGs) ---
  EA ea;
  ea.whhF = whhF_h; ea.whhR = whhR_h;
  ea.xpF = xp_f; ea.xpR = xp_r;
  ea.h = hbuf; ea.enc_out = enc_out;
  ea.dh0 = dh + (size_t)TDEC*NB*DH;
  ea.dc = dc;
  ea.flags = eflags;
  hipFuncSetAttribute((const void*)enc_seq,
                      hipFuncAttributeMaxDynamicSharedMemorySize, LDS_ENC);
  enc_seq<<<dim3(64), 256, LDS_ENC, stream>>>(ea);

  // --- eqT = (enc_out @ wi)^T, eo2T = (enc_out @ wo_st)^T (transposed via operand swap) ---
  gemm128h<<<dim3(25,8),256,0,stream>>>(wiT_h, DH, enc_out, DH, zb, eqT_h, TB3, DH, 1024, 3200);
  gemm128h<<<dim3(25,8),256,0,stream>>>(wo_h, 2048, enc_out, DH, zb, eo2T_h, TB3, 1024, 1024, 3200);
  score0T<<<dim3(TSRC),256,0,stream>>>(eqT_h, dh + (size_t)TDEC*NB*DH,
                                       scores + (size_t)TDEC*TSRC*NB);

  // --- decoder (persistent, 192 WGs, 2 hops/step) ---
  DA da;
  da.wo = wo_h; da.wdh = wdh_h; da.w3c = w3c;
  da.eqT = eqT_h; da.eo2T = eo2T_h;
  da.pp = peproj;
  da.dh = dh; da.dc = dc;
  da.ct = ct;
  da.scores = scores;
  da.hdec = hdec;
  da.flags = dflags;
  hipFuncSetAttribute((const void*)dec_seq,
                      hipFuncAttributeMaxDynamicSharedMemorySize, LDS_TOT);
  dec_seq<<<dim3(192), 256, LDS_TOT, stream>>>(da);

  // --- generator + log-softmax ---
  gemm128<<<dim3(GVP/128,25),256,0,stream>>>(hdec, DH, genw_h, DH, genb, out, GV, DH, 3136, GV, NB);
  lsm<<<3136,256,0,stream>>>(out);
}

// Round 14
// 2246.456 us; speedup vs baseline: 1.6800x; 1.6705x over previous
//
#include <hip/hip_runtime.h>
#include <cstdint>
#include <cmath>

// ---------------- dims ----------------
#define NB    64
#define EMBD  300
#define EMBP  320
#define EH    512
#define DH    1024
#define GV    23262
#define GVP   23296
#define TSRC  50
#define TDEC  49
#define LDS_SCR 131072
#define LDS_TOT (131072 + 16384 + 256)
#define LDS_ENC (65536 + 16384 + 256)
#define FS    32      // ints between flags (128 B)

typedef __attribute__((ext_vector_type(8))) _Float16 f16x8;
typedef __attribute__((ext_vector_type(4))) float f32x4;

__device__ __forceinline__ float sigm(float x){ return 1.f/(1.f+expf(-x)); }

// ---- write-through (agent-scope relaxed atomic) stores, packed ----
__device__ __forceinline__ void cohS16(_Float16* p, _Float16 v){
  union { _Float16 f; unsigned short u; } c; c.f = v;
  __hip_atomic_store((unsigned short*)p, c.u, __ATOMIC_RELAXED, __HIP_MEMORY_SCOPE_AGENT);
}
__device__ __forceinline__ void cohS32(float* p, float v){
  __hip_atomic_store(p, v, __ATOMIC_RELAXED, __HIP_MEMORY_SCOPE_AGENT);
}
__device__ __forceinline__ void cohS64(void* p, unsigned long long v){
  __hip_atomic_store((unsigned long long*)p, v, __ATOMIC_RELAXED, __HIP_MEMORY_SCOPE_AGENT);
}
__device__ __forceinline__ void cohS32u(void* p, unsigned int v){
  __hip_atomic_store((unsigned int*)p, v, __ATOMIC_RELAXED, __HIP_MEMORY_SCOPE_AGENT);
}
__device__ __forceinline__ unsigned short h2u(float f){
  union { _Float16 h; unsigned short u; } c; c.h = (_Float16)f; return c.u;
}
__device__ __forceinline__ unsigned long long pk4h(float a, float b, float c, float d){
  return (unsigned long long)h2u(a) | ((unsigned long long)h2u(b)<<16)
       | ((unsigned long long)h2u(c)<<32) | ((unsigned long long)h2u(d)<<48);
}
__device__ __forceinline__ unsigned int pk2h(float a, float b){
  return (unsigned int)h2u(a) | ((unsigned int)h2u(b)<<16);
}
__device__ __forceinline__ unsigned long long pk2f(float a, float b){
  union { float f; unsigned int u; } x, y; x.f = a; y.f = b;
  return (unsigned long long)x.u | ((unsigned long long)y.u<<32);
}

// ---- flags: producers post own flag; consumers poll relaxed. No HW fence:
// all inter-step data lives in t-rotated write-once buffers (descending addr),
// so the consumer's first touch is a compulsory miss fetching post-store data.
__device__ __forceinline__ int ldF(int* p){
  return __hip_atomic_load(p, __ATOMIC_RELAXED, __HIP_MEMORY_SCOPE_AGENT);
}
__device__ __forceinline__ void stF(int* p, int v){
  __hip_atomic_store(p, v, __ATOMIC_RELAXED, __HIP_MEMORY_SCOPE_AGENT);
}
__device__ __forceinline__ void post(int* flagArr, int idx, int epoch){
  __syncthreads();   // drain this WG's write-through stores (vmcnt)
  if (threadIdx.x == 0) stF(flagArr + idx*FS, epoch);
}
__device__ __forceinline__ void flagWaitIdx(int* flagArr, int myIdx, bool active, int epoch)
{
  if (active) {
    int* p = flagArr + myIdx*FS;
    while (ldF(p) < epoch) __builtin_amdgcn_s_sleep(1);
  }
  __syncthreads();
  __atomic_signal_fence(__ATOMIC_SEQ_CST);
}

// ---- stage a [nrows][ncols] fp16 tile into LDS with XOR-16B swizzle ----
__device__ __forceinline__ void stageW(char* dst, const _Float16* __restrict__ src,
                                       int srcld, int nrows, int ncols, int tid)
{
  const int nch = ncols >> 3;
  for (int i = tid; i < nrows*nch; i += 256) {
    int row = i / nch, c = i - row*nch;
    *(f16x8*)(dst + row*ncols*2 + ((c*16) ^ ((row&7)<<4))) =
        *(const f16x8*)(src + (size_t)row*srcld + c*8);
  }
}

// 64x16 MFMA tile: acc += A[64][K](plain cached) @ B[16][K](LDS swizzled)^T
template<int K>
__device__ __forceinline__ void mm16L(f32x4 (&acc)[4],
    const _Float16* __restrict__ A, int lda,
    const char* ldsB, int rowbytes, int koffB, int lane)
{
  const int r = lane & 15, q = lane >> 4;
  const _Float16* a0 = A + r*lda + q*8;
  const char* b0 = ldsB + r*rowbytes + koffB;
  const int sw = (r & 7) << 4;
#pragma unroll
  for (int g = 0; g < K/256; ++g) {
    f16x8 av[8][4], bv[8];
#pragma unroll
    for (int s = 0; s < 8; ++s) {
      int sl = g*8 + s;
      bv[s] = *(const f16x8*)(b0 + ((sl*64 + q*16) ^ sw));
#pragma unroll
      for (int m = 0; m < 4; ++m)
        av[s][m] = *(const f16x8*)(a0 + m*16*lda + sl*32);
    }
#pragma unroll
    for (int s = 0; s < 8; ++s)
#pragma unroll
      for (int m = 0; m < 4; ++m)
        acc[m] = __builtin_amdgcn_mfma_f32_16x16x32_f16(av[s][m], bv[s], acc[m], 0, 0, 0);
  }
}

// ---------------- prep kernels ----------------
__global__ void cvt16s(const float* __restrict__ src, _Float16* __restrict__ dst,
                       int rows, int sld, int scols, int dcols)
{
  int idx = blockIdx.x*256 + threadIdx.x;
  if (idx >= rows*dcols) return;
  int c = idx % dcols, rr = idx / dcols;
  dst[idx] = (c < scols) ? (_Float16)src[(size_t)rr*sld + c] : (_Float16)0.f;
}

__global__ void cvt16t(const float* __restrict__ src, _Float16* __restrict__ dst, int n)
{
  int idx = blockIdx.x*256 + threadIdx.x;
  if (idx >= n*n) return;
  int rr = idx / n, c = idx - rr*n;
  dst[(size_t)c*n + rr] = (_Float16)src[idx];
}

__global__ void addb(const float* __restrict__ a, const float* __restrict__ b,
                     float* __restrict__ o, int n)
{
  int i = blockIdx.x*256 + threadIdx.x;
  if (i < n) o[i] = a[i] + b[i];
}

__global__ void k_embed(const int* __restrict__ src, const int* __restrict__ trg,
                        const float* __restrict__ eemb, const float* __restrict__ demb,
                        _Float16* __restrict__ x_h, _Float16* __restrict__ xrev_h,
                        _Float16* __restrict__ pe_h)
{
  int idx = blockIdx.x*256 + threadIdx.x;
  const int tot1 = TSRC*NB*EMBP;
  const int tot2 = TDEC*NB*EMBP;
  if (idx < tot1) {
    int e = idx % EMBP, rb = idx / EMBP;
    int t = rb >> 6, b = rb & 63;
    float v = 0.f;
    if (e < EMBD) v = eemb[(size_t)src[rb]*EMBD + e];
    _Float16 hv = (_Float16)v;
    x_h[idx] = hv;
    xrev_h[(size_t)((TSRC-1-t)*NB + b)*EMBP + e] = hv;
  } else if (idx < tot1 + tot2) {
    int k = idx - tot1;
    int e = k % EMBP, rb = k / EMBP;
    float v = 0.f;
    if (e < EMBD) v = demb[(size_t)trg[rb]*EMBD + e];
    pe_h[k] = (_Float16)v;
  }
}

// ---- bijective XCD-chunked block swizzle (m204 formula): consecutive wg on one
// XCD -> A-row-panel + W-panel L2 reuse for the generator GEMM ----
__device__ __forceinline__ void swz_block(int& m0, int& n0)
{
  int nwg = gridDim.x*gridDim.y;
  int flat = blockIdx.y*gridDim.x + blockIdx.x;
  int q = nwg >> 3, rr = nwg & 7;
  int xcd = flat & 7, pos = flat >> 3;
  int wg = (xcd < rr) ? xcd*(q+1) + pos : rr*(q+1) + (xcd-rr)*q + pos;
  m0 = (wg / gridDim.x) * 128;
  n0 = (wg % gridDim.x) * 128;
}

// ---------------- big tiled GEMM (throughput path), fp16 in / f32 out ----------------
__global__ __launch_bounds__(256) void gemm128(
    const _Float16* __restrict__ A, int lda,
    const _Float16* __restrict__ W, int ldw,
    const float* __restrict__ bias,
    float* __restrict__ out, int ldo,
    int K, int mvalid, int nvalid, int rowoff)
{
  __shared__ _Float16 As[128*64];
  __shared__ _Float16 Bs[128*64];
  const int tid = threadIdx.x;
  int m0, n0;
  swz_block(m0, n0);
  const int w = tid >> 6, lane = tid & 63, r = lane & 15, q = lane >> 4;
  const int mw = (w >> 1)*64, nw = (w & 1)*64;
  f32x4 acc[4][4];
#pragma unroll
  for (int mi=0; mi<4; ++mi)
#pragma unroll
    for (int ni=0; ni<4; ++ni) acc[mi][ni] = 0.f;

  for (int kt = 0; kt < K; kt += 64) {
    f16x8 ra[4], rb[4];
#pragma unroll
    for (int j = 0; j < 4; ++j) {
      int c = j*256 + tid, row = c >> 3, cc = c & 7;
      ra[j] = *(const f16x8*)(A + (size_t)(m0+row)*lda + kt + cc*8);
      rb[j] = *(const f16x8*)(W + (size_t)(n0+row)*ldw + kt + cc*8);
    }
    __syncthreads();
#pragma unroll
    for (int j = 0; j < 4; ++j) {
      int c = j*256 + tid, row = c >> 3, cc = c & 7;
      int sw = cc ^ (row & 7);
      *(f16x8*)((char*)As + row*128 + (sw<<4)) = ra[j];
      *(f16x8*)((char*)Bs + row*128 + (sw<<4)) = rb[j];
    }
    __syncthreads();
#pragma unroll
    for (int kk = 0; kk < 64; kk += 32) {
      int ch = (kk >> 3) + q;
      f16x8 av[4], bv[4];
#pragma unroll
      for (int mi=0; mi<4; ++mi) {
        int row = mw + mi*16 + r;
        av[mi] = *(const f16x8*)((char*)As + row*128 + ((ch ^ (row&7))<<4));
      }
#pragma unroll
      for (int ni=0; ni<4; ++ni) {
        int row = nw + ni*16 + r;
        bv[ni] = *(const f16x8*)((char*)Bs + row*128 + ((ch ^ (row&7))<<4));
      }
#pragma unroll
      for (int mi=0; mi<4; ++mi)
#pragma unroll
        for (int ni=0; ni<4; ++ni)
          acc[mi][ni] = __builtin_amdgcn_mfma_f32_16x16x32_f16(av[mi], bv[ni], acc[mi][ni], 0,0,0);
    }
  }
#pragma unroll
  for (int mi=0; mi<4; ++mi)
#pragma unroll
    for (int ni=0; ni<4; ++ni)
#pragma unroll
      for (int e=0; e<4; ++e) {
        int mrow = m0 + mw + mi*16 + q*4 + e;
        int col  = n0 + nw + ni*16 + r;
        if (mrow < mvalid && col < nvalid)
          out[(size_t)(mrow + rowoff)*ldo + col] = acc[mi][ni][e] + bias[col];
      }
}

// same GEMM but fp16 output (eq, eo2, peproj)
__global__ __launch_bounds__(256) void gemm128h(
    const _Float16* __restrict__ A, int lda,
    const _Float16* __restrict__ W, int ldw,
    const float* __restrict__ bias,
    _Float16* __restrict__ out, int ldo,
    int K, int mvalid, int nvalid)
{
  __shared__ _Float16 As[128*64];
  __shared__ _Float16 Bs[128*64];
  const int tid = threadIdx.x;
  int m0, n0;
  swz_block(m0, n0);
  const int w = tid >> 6, lane = tid & 63, r = lane & 15, q = lane >> 4;
  const int mw = (w >> 1)*64, nw = (w & 1)*64;
  f32x4 acc[4][4];
#pragma unroll
  for (int mi=0; mi<4; ++mi)
#pragma unroll
    for (int ni=0; ni<4; ++ni) acc[mi][ni] = 0.f;

  for (int kt = 0; kt < K; kt += 64) {
    f16x8 ra[4], rb[4];
#pragma unroll
    for (int j = 0; j < 4; ++j) {
      int c = j*256 + tid, row = c >> 3, cc = c & 7;
      ra[j] = *(const f16x8*)(A + (size_t)(m0+row)*lda + kt + cc*8);
      rb[j] = *(const f16x8*)(W + (size_t)(n0+row)*ldw + kt + cc*8);
    }
    __syncthreads();
#pragma unroll
    for (int j = 0; j < 4; ++j) {
      int c = j*256 + tid, row = c >> 3, cc = c & 7;
      int sw = cc ^ (row & 7);
      *(f16x8*)((char*)As + row*128 + (sw<<4)) = ra[j];
      *(f16x8*)((char*)Bs + row*128 + (sw<<4)) = rb[j];
    }
    __syncthreads();
#pragma unroll
    for (int kk = 0; kk < 64; kk += 32) {
      int ch = (kk >> 3) + q;
      f16x8 av[4], bv[4];
#pragma unroll
      for (int mi=0; mi<4; ++mi) {
        int row = mw + mi*16 + r;
        av[mi] = *(const f16x8*)((char*)As + row*128 + ((ch ^ (row&7))<<4));
      }
#pragma unroll
      for (int ni=0; ni<4; ++ni) {
        int row = nw + ni*16 + r;
        bv[ni] = *(const f16x8*)((char*)Bs + row*128 + ((ch ^ (row&7))<<4));
      }
#pragma unroll
      for (int mi=0; mi<4; ++mi)
#pragma unroll
        for (int ni=0; ni<4; ++ni)
          acc[mi][ni] = __builtin_amdgcn_mfma_f32_16x16x32_f16(av[mi], bv[ni], acc[mi][ni], 0,0,0);
    }
  }
#pragma unroll
  for (int mi=0; mi<4; ++mi)
#pragma unroll
    for (int ni=0; ni<4; ++ni)
#pragma unroll
      for (int e=0; e<4; ++e) {
        int mrow = m0 + mw + mi*16 + q*4 + e;
        int col  = n0 + nw + ni*16 + r;
        if (mrow < mvalid && col < nvalid)
          out[(size_t)mrow*ldo + col] = (_Float16)(acc[mi][ni][e] + bias[col]);
      }
}

// ---------------- persistent encoder (64 WGs, 1 hop/step, rotated h) ----------------
struct EA {
  const _Float16 *whhF, *whhR;   // [2048][512]
  const float *xpF, *xpR;        // [50*64][2048] (bias folded)
  _Float16 *h;                   // [TSRC+1 slots][2 dir][64][512]; slot TSRC zeroed
  _Float16 *enc_out;             // [50][64][1024]
  _Float16 *dh0;                 // dh slot TDEC (decoder handoff)
  float *dc;                     // [64][1024]
  int *flags;                    // 64
};

__global__ __launch_bounds__(256, 1) void enc_seq(EA a)
{
  extern __shared__ char lds[];
  const int tid = threadIdx.x, w = tid >> 6, lane = tid & 63;
  const int wgid = blockIdx.x;
  const int r = lane & 15, q4 = lane >> 4;
  float (*sm4)[64][16] = (float(*)[64][16])(lds + 65536);

  const int dir = wgid >> 5, j0 = (wgid & 31) << 4;
  const _Float16* whh = dir ? a.whhR : a.whhF;
  for (int g = 0; g < 4; ++g)
    stageW(lds + g*16384, whh + (size_t)(g*EH + j0)*EH, EH, 16, 512, tid);
  __syncthreads();

  const int b = tid >> 2, jq = (tid & 3) * 4;
  float creg[4] = {0.f, 0.f, 0.f, 0.f};
  const float* xpbase = dir ? a.xpR : a.xpF;

  for (int t = 0; t < TSRC; ++t) {
    float xr[4][4];
#pragma unroll
    for (int g = 0; g < 4; ++g)
#pragma unroll
      for (int k = 0; k < 4; ++k)
        xr[g][k] = xpbase[((size_t)t*NB + b)*2048 + g*EH + j0 + jq + k];
    if (t) flagWaitIdx(a.flags, dir*32 + tid, tid < 32, t);
    const _Float16* H = a.h + ((size_t)(TSRC-t)*2 + dir)*NB*EH;
    f32x4 acc[4];
#pragma unroll
    for (int m=0;m<4;++m) acc[m] = 0.f;
    mm16L<EH>(acc, H, EH, lds + w*16384, 1024, 0, lane);
#pragma unroll
    for (int m=0;m<4;++m)
#pragma unroll
      for (int e=0;e<4;++e) sm4[w][m*16 + q4*4 + e][r] = acc[m][e];
    __syncthreads();
    _Float16* Ho = a.h + ((size_t)(TSRC-1-t)*2 + dir)*NB*EH;
    const int erow = dir ? (TSRC-1 - t) : t;
    float hv[4];
#pragma unroll
    for (int k = 0; k < 4; ++k) {
      int jj = jq + k;
      float gi = sm4[0][b][jj] + xr[0][k];
      float gf = sm4[1][b][jj] + xr[1][k];
      float gg = sm4[2][b][jj] + xr[2][k];
      float go = sm4[3][b][jj] + xr[3][k];
      float cn = sigm(gf)*creg[k] + sigm(gi)*tanhf(gg);
      creg[k] = cn;
      hv[k] = sigm(go)*tanhf(cn);
    }
    cohS64(Ho + b*EH + j0 + jq, pk4h(hv[0],hv[1],hv[2],hv[3]));
    cohS64(a.enc_out + ((size_t)erow*NB + b)*DH + dir*EH + j0 + jq, pk4h(hv[0],hv[1],hv[2],hv[3]));
    if (t == TSRC-1) {
#pragma unroll
      for (int k = 0; k < 4; ++k) {
        int j = j0 + jq + k;
        cohS16(a.dh0 + b*DH + 2*j + dir, (_Float16)hv[k]);
        cohS32(a.dc + b*DH + 2*j + dir, creg[k]);
      }
    }
    post(a.flags, wgid, t+1);
  }
}

// ---------------- persistent decoder (224 WGs, 2 exposed hops/step) ----------------
// roles: 0-63 P2 (scores+softmax+ctx via eq/eo2; assembles ct after FCpre) |
//        64-95 C (wodhdh = wo_dh·dh, 32 cols each; parallel with P2) |
//        96-223 D (wdh·dh + w3c·ct + pp, LSTM)
// chain: FD -> {P2 ctx || C wodhdh -> FCpre} -> P2 ct -> FB -> D -> FD
struct DA {
  const _Float16 *wo;            // [1024][2048] (cols 1024.. = dh part)
  const _Float16 *wdh;           // [4096][1024] dec_Whh
  const _Float16 *w3c;           // [4096][1024] dWih ct-part
  const _Float16 *eq;            // [50][64][1024] enc_out @ wi (row-major)
  const _Float16 *eo2;           // [50][64][1024] enc_out @ wo_st (row-major)
  const _Float16 *pp;            // [49*64][4096] pe-proj + biases (fp16)
  _Float16 *dh;                  // [TDEC+1 slots][64][1024]; slot TDEC = enc handoff
  float *dc;                     // [64][1024] (enc handoff)
  _Float16 *ct;                  // [TDEC+1 slots][64][1024]
  float *wdd;                    // [TDEC+1 slots][64][1024] f32 (wo_dh·dh)
  _Float16 *hdec;                // [3200][1024]
  int *flags;                    // FB 64 | FCP 32 | FD 128
};

__global__ __launch_bounds__(256, 1) void dec_seq(DA a)
{
  extern __shared__ char lds[];
  const int tid = threadIdx.x, w = tid >> 6, lane = tid & 63;
  const int wgid = blockIdx.x;
  const int r = lane & 15, q4 = lane >> 4;
  float (*sm4)[64][16] = (float(*)[64][16])(lds + LDS_SCR);
  float* qs = (float*)(lds + LDS_SCR);           // P2 dh row (aliases sm4)
  float* sc = (float*)(lds + LDS_SCR + 16384);

  int* FB  = a.flags;
  int* FCP = FB + 64*FS;
  int* FD  = FCP + 32*FS;

  // ---- stage weights ----
  if (wgid >= 64 && wgid < 96) {
    // C: wo_dh rows [32][1024] for cols (wgid-64)*32 ..
    stageW(lds, a.wo + (size_t)((wgid-64)*32)*2048 + 1024, 2048, 32, 1024, tid);
  } else if (wgid >= 96) {
    int i = wgid - 96;
    for (int g = 0; g < 4; ++g)
      stageW(lds + g*8*2048, a.wdh + (size_t)(g*1024 + i*8)*DH, DH, 8, 1024, tid);
    for (int g = 0; g < 4; ++g)
      stageW(lds + 65536 + g*8*2048, a.w3c + (size_t)(g*1024 + i*8)*DH, DH, 8, 1024, tid);
  }
  __syncthreads();

  const bool isP2 = (wgid < 64);
  const bool isC  = (wgid >= 64 && wgid < 96);
  const bool isD  = (wgid >= 96);
  float dcreg[2] = {0.f, 0.f};

  for (int t = 0; t < TDEC; ++t) {
    const size_t cur = (size_t)(TDEC - t)*NB*DH;
    const size_t nxt = (size_t)(TDEC - 1 - t)*NB*DH;
    const _Float16* dhC = a.dh + cur;

    // ---- C: wodhdh = wo_dh · dh (parallel with P2's ctx work) ----
    if (isC) {
      if (t) flagWaitIdx(FD, tid, tid < 128, t);
      const int col0 = (wgid - 64)*32;
      const int cs = w >> 1, kh = w & 1;
      f32x4 acc[4];
#pragma unroll
      for (int m=0;m<4;++m) acc[m] = 0.f;
      mm16L<512>(acc, dhC + kh*512, DH, lds + cs*16*2048, 2048, kh*1024, lane);
#pragma unroll
      for (int m=0;m<4;++m)
#pragma unroll
        for (int e=0;e<4;++e) sm4[w][m*16 + q4*4 + e][r] = acc[m][e];
      __syncthreads();
      for (int p = tid; p < 2048; p += 256) {
        int b = p >> 5, cc = p & 31;
        float v1, v2;
        int c1 = (cc & 30);
        v1 = sm4[((c1)>>4)*2][b][(c1)&15] + sm4[((c1)>>4)*2+1][b][(c1)&15];
        v2 = sm4[((c1+1)>>4)*2][b][(c1+1)&15] + sm4[((c1+1)>>4)*2+1][b][(c1+1)&15];
        if ((cc & 1) == 0)
          cohS64(a.wdd + cur + b*DH + col0 + c1, pk2f(v1, v2));
      }
      post(FCP, wgid - 64, t+1);
    }

    // ---- P2: scores + softmax + ctx (eo2); after FCpre assemble ct ----
    if (isP2) {
      if (t) flagWaitIdx(FD, tid, tid < 128, t);
      const int b = wgid;
      if (tid < 128) {
        f16x8 v = *(const f16x8*)(dhC + b*DH + tid*8);
#pragma unroll
        for (int k = 0; k < 8; ++k) qs[tid*8 + k] = (float)v[k];
      }
      __syncthreads();
      for (int tt = w; tt < TSRC; tt += 4) {
        const _Float16* er = a.eq + ((size_t)tt*NB + b)*DH + lane*16;
        const float* qq = qs + lane*16;
        f16x8 e0 = *(const f16x8*)(er);
        f16x8 e1 = *(const f16x8*)(er + 8);
        float s = 0.f;
#pragma unroll
        for (int ii=0; ii<8; ++ii) s += (float)e0[ii]*qq[ii];
#pragma unroll
        for (int ii=0; ii<8; ++ii) s += (float)e1[ii]*qq[8+ii];
#pragma unroll
        for (int o=32; o; o>>=1) s += __shfl_xor(s, o);
        if (lane == 0) sc[tt] = s;
      }
      __syncthreads();
      float mx = -1e30f;
      for (int tt=0; tt<TSRC; ++tt) mx = fmaxf(mx, sc[tt]);
      __syncthreads();
      if (tid < TSRC) sc[tid] = expf(sc[tid] - mx);
      __syncthreads();
      float s50 = 0.f;
      for (int tt=0; tt<TSRC; ++tt) s50 += sc[tt];
      const float inv = 1.f/s50;
      const int c0 = tid*4;
      float a0=0.f, a1=0.f, a2=0.f, a3=0.f;
      for (int tt=0; tt<TSRC; ++tt) {
        float wt = sc[tt];
        const _Float16* er = a.eo2 + ((size_t)tt*NB + b)*DH + c0;
        a0 += wt*(float)er[0]; a1 += wt*(float)er[1];
        a2 += wt*(float)er[2]; a3 += wt*(float)er[3];
      }
      // wait for C's wodhdh, then assemble ct = tanh(ctx + wodhdh)
      flagWaitIdx(FCP, tid, tid < 32, t+1);
      f32x4 wd = *(const f32x4*)(a.wdd + cur + b*DH + c0);
      float v0 = tanhf(a0*inv + wd[0]);
      float v1 = tanhf(a1*inv + wd[1]);
      float v2 = tanhf(a2*inv + wd[2]);
      float v3 = tanhf(a3*inv + wd[3]);
      cohS64(a.ct + cur + b*DH + c0, pk4h(v0, v1, v2, v3));
      post(FB, wgid, t+1);
    }

    // ---- D: gates = wdh·dh (pre-FB) + w3c·ct (post-FB) + pp; LSTM ----
    if (isD) {
      const int i = wgid - 96;
      if (t) flagWaitIdx(FD, tid, tid < 128, t);
      const int b = tid >> 2, j0 = i*8, jj2 = (tid & 3)*2;
      if (t == 0) {
        dcreg[0] = a.dc[b*DH + j0 + jj2];
        dcreg[1] = a.dc[b*DH + j0 + jj2 + 1];
      }
      const int cs = w >> 1, kh = w & 1;
      f32x4 acc[4];
#pragma unroll
      for (int m=0;m<4;++m) acc[m] = 0.f;
      mm16L<512>(acc, dhC + kh*512, DH, lds + cs*16*2048, 2048, kh*1024, lane);
      float ppv[4][2];
#pragma unroll
      for (int g = 0; g < 4; ++g)
#pragma unroll
        for (int k = 0; k < 2; ++k)
          ppv[g][k] = (float)a.pp[((size_t)t*NB + b)*4096 + g*DH + j0 + jj2 + k];
      flagWaitIdx(FB, tid, tid < 64, t+1);
      mm16L<512>(acc, a.ct + cur + kh*512, DH, lds + 65536 + cs*16*2048, 2048, kh*1024, lane);
#pragma unroll
      for (int m=0;m<4;++m)
#pragma unroll
        for (int e=0;e<4;++e) sm4[w][m*16 + q4*4 + e][r] = acc[m][e];
      __syncthreads();
      float hv[2];
#pragma unroll
      for (int k = 0; k < 2; ++k) {
        int jj = jj2 + k;
        float gi = sm4[0][b][jj]   + sm4[1][b][jj]   + ppv[0][k];
        float gf = sm4[0][b][8+jj] + sm4[1][b][8+jj] + ppv[1][k];
        float gg = sm4[2][b][jj]   + sm4[3][b][jj]   + ppv[2][k];
        float go = sm4[2][b][8+jj] + sm4[3][b][8+jj] + ppv[3][k];
        float cn = sigm(gf)*dcreg[k] + sigm(gi)*tanhf(gg);
        dcreg[k] = cn;
        hv[k] = sigm(go)*tanhf(cn);
      }
      cohS32u(a.dh + nxt + b*DH + j0 + jj2, pk2h(hv[0], hv[1]));
      post(FD, i, t+1);
      // hdec only read after kernel end -> plain store, off the drain path
      *(unsigned int*)(a.hdec + ((size_t)t*NB + b)*DH + j0 + jj2) = pk2h(hv[0], hv[1]);
    }
  }
}

// ---------------- in-place log-softmax (online max+sum) ----------------
__global__ __launch_bounds__(256) void lsm(float* __restrict__ out)
{
  const int row = NB + blockIdx.x;
  float* p = out + (size_t)row*GV;
  const int tid = threadIdx.x;
  __shared__ float rm[4], rl[4];
  float m = -1e30f, l = 0.f;
  for (int i = tid; i < GV; i += 256) {
    float v = p[i];
    float M = fmaxf(m, v);
    l = l*expf(m - M) + expf(v - M);
    m = M;
  }
  for (int off=32; off; off>>=1) {
    float m2 = __shfl_down(m, off), l2 = __shfl_down(l, off);
    float M = fmaxf(m, m2);
    l = l*expf(m - M) + l2*expf(m2 - M);
    m = M;
  }
  if ((tid & 63) == 0) { rm[tid>>6] = m; rl[tid>>6] = l; }
  __syncthreads();
  m = rm[0]; l = rl[0];
#pragma unroll
  for (int k=1; k<4; ++k) {
    float M = fmaxf(m, rm[k]);
    l = l*expf(m - M) + rl[k]*expf(rm[k] - M);
    m = M;
  }
  float lse = m + logf(l);
  for (int i = tid; i < GV; i += 256) p[i] -= lse;
}

// ---------------- host ----------------
extern "C" void kernel_launch(void* const* d_in, const int* in_sizes, int n_in,
                              void* d_out, int out_size, void* d_ws, size_t ws_size,
                              hipStream_t stream)
{
  const int*   src  = (const int*)d_in[0];
  const int*   trg  = (const int*)d_in[1];
  const float* WihF = (const float*)d_in[2];
  const float* WhhF = (const float*)d_in[3];
  const float* bihF = (const float*)d_in[4];
  const float* bhhF = (const float*)d_in[5];
  const float* WihR = (const float*)d_in[6];
  const float* WhhR = (const float*)d_in[7];
  const float* bihR = (const float*)d_in[8];
  const float* bhhR = (const float*)d_in[9];
  const float* dWih = (const float*)d_in[10];
  const float* dWhh = (const float*)d_in[11];
  const float* dbih = (const float*)d_in[12];
  const float* dbhh = (const float*)d_in[13];
  const float* eemb = (const float*)d_in[14];
  const float* demb = (const float*)d_in[15];
  const float* wi   = (const float*)d_in[16];
  const float* wo   = (const float*)d_in[17];
  const float* genw = (const float*)d_in[18];
  const float* genb = (const float*)d_in[19];
  float* out = (float*)d_out;

  char* ws = (char*)d_ws;
  size_t off = 0;
  auto alloc = [&](size_t bytes)->char* {
    char* p = ws + off; off = (off + bytes + 255) & ~(size_t)255; return p;
  };
  _Float16* x_h    = (_Float16*)alloc((size_t)TSRC*NB*EMBP*2);
  _Float16* xrev_h = (_Float16*)alloc((size_t)TSRC*NB*EMBP*2);
  _Float16* pe_h   = (_Float16*)alloc((size_t)TDEC*NB*EMBP*2);
  _Float16* wihF_h = (_Float16*)alloc((size_t)2048*EMBP*2);
  _Float16* wihR_h = (_Float16*)alloc((size_t)2048*EMBP*2);
  _Float16* whhF_h = (_Float16*)alloc((size_t)2048*EH*2);
  _Float16* whhR_h = (_Float16*)alloc((size_t)2048*EH*2);
  _Float16* wdh_h  = (_Float16*)alloc((size_t)4096*DH*2);
  _Float16* wo_h   = (_Float16*)alloc((size_t)DH*2048*2);
  _Float16* w3c    = (_Float16*)alloc((size_t)4096*DH*2);
  _Float16* w3pe   = (_Float16*)alloc((size_t)4096*EMBP*2);
  _Float16* wiT_h  = (_Float16*)alloc((size_t)DH*DH*2);
  _Float16* genw_h = (_Float16*)alloc((size_t)GVP*DH*2);
  float* b4f   = (float*)alloc(2048*4);
  float* b4r   = (float*)alloc(2048*4);
  float* db4   = (float*)alloc(4096*4);
  float* zb    = (float*)alloc(DH*4);
  float* xp_f  = (float*)alloc((size_t)TSRC*NB*2048*4);
  float* xp_r  = (float*)alloc((size_t)TSRC*NB*2048*4);
  _Float16* peproj = (_Float16*)alloc((size_t)TDEC*NB*4096*2);
  _Float16* enc_out = (_Float16*)alloc((size_t)TSRC*NB*DH*2);
  _Float16* eq_h  = (_Float16*)alloc((size_t)TSRC*NB*DH*2);
  _Float16* eo2_h = (_Float16*)alloc((size_t)TSRC*NB*DH*2);
  _Float16* hbuf = (_Float16*)alloc((size_t)(TSRC+1)*2*NB*EH*2);
  _Float16* dh = (_Float16*)alloc((size_t)(TDEC+1)*NB*DH*2);
  float* dc = (float*)alloc((size_t)NB*DH*4);
  _Float16* ct = (_Float16*)alloc((size_t)(TDEC+1)*NB*DH*2);
  float* wdd = (float*)alloc((size_t)(TDEC+1)*NB*DH*4);
  _Float16* hdec = (_Float16*)alloc((size_t)3200*DH*2);
  int* eflags = (int*)alloc(64*FS*4);
  int* dflags = (int*)alloc(224*FS*4);
  (void)in_sizes; (void)n_in; (void)out_size; (void)ws_size;

  // --- init / zero state (graph replays don't re-poison) ---
  hipMemsetAsync(hbuf + (size_t)TSRC*2*NB*EH, 0, (size_t)2*NB*EH*2, stream);  // h slot TSRC
  hipMemsetAsync(hdec + (size_t)3136*DH, 0, (size_t)64*DH*2, stream);
  hipMemsetAsync(genw_h + (size_t)GV*DH, 0, (size_t)(GVP-GV)*DH*2, stream);
  hipMemsetAsync(out, 0, (size_t)NB*GV*4, stream);
  hipMemsetAsync(zb, 0, DH*4, stream);
  hipMemsetAsync(eflags, 0, 64*FS*4, stream);
  hipMemsetAsync(dflags, 0, 224*FS*4, stream);

  auto cgrid = [](size_t n){ return dim3((unsigned)((n + 255)/256)); };

  // --- weight conversion (fp16) ---
  cvt16s<<<cgrid((size_t)2048*EMBP),256,0,stream>>>(WihF, wihF_h, 2048, EMBD, EMBD, EMBP);
  cvt16s<<<cgrid((size_t)2048*EMBP),256,0,stream>>>(WihR, wihR_h, 2048, EMBD, EMBD, EMBP);
  cvt16s<<<cgrid((size_t)2048*EH),256,0,stream>>>(WhhF, whhF_h, 2048, EH, EH, EH);
  cvt16s<<<cgrid((size_t)2048*EH),256,0,stream>>>(WhhR, whhR_h, 2048, EH, EH, EH);
  cvt16s<<<cgrid((size_t)4096*DH),256,0,stream>>>(dWhh, wdh_h, 4096, DH, DH, DH);
  cvt16s<<<cgrid((size_t)DH*2048),256,0,stream>>>(wo, wo_h, DH, 2048, 2048, 2048);
  cvt16s<<<cgrid((size_t)4096*DH),256,0,stream>>>(dWih, w3c, 4096, 1324, 1024, 1024);
  cvt16s<<<cgrid((size_t)4096*EMBP),256,0,stream>>>(dWih + 1024, w3pe, 4096, 1324, 300, EMBP);
  cvt16t<<<cgrid((size_t)DH*DH),256,0,stream>>>(wi, wiT_h, DH);
  cvt16s<<<cgrid((size_t)GV*DH),256,0,stream>>>(genw, genw_h, GV, DH, DH, DH);
  addb<<<cgrid(2048),256,0,stream>>>(bihF, bhhF, b4f, 2048);
  addb<<<cgrid(2048),256,0,stream>>>(bihR, bhhR, b4r, 2048);
  addb<<<cgrid(4096),256,0,stream>>>(dbih, dbhh, db4, 4096);
  k_embed<<<cgrid((size_t)(TSRC+TDEC)*NB*EMBP),256,0,stream>>>(src, trg, eemb, demb, x_h, xrev_h, pe_h);

  // --- input projections ---
  gemm128<<<dim3(16,25),256,0,stream>>>(x_h,    EMBP, wihF_h, EMBP, b4f, xp_f, 2048, EMBP, 3200, 2048, 0);
  gemm128<<<dim3(16,25),256,0,stream>>>(xrev_h, EMBP, wihR_h, EMBP, b4r, xp_r, 2048, EMBP, 3200, 2048, 0);
  gemm128h<<<dim3(32,25),256,0,stream>>>(pe_h, EMBP, w3pe, EMBP, db4, peproj, 4096, EMBP, 3136, 4096);

  // --- encoder (persistent, 64 WGs) ---
  EA ea;
  ea.whhF = whhF_h; ea.whhR = whhR_h;
  ea.xpF = xp_f; ea.xpR = xp_r;
  ea.h = hbuf; ea.enc_out = enc_out;
  ea.dh0 = dh + (size_t)TDEC*NB*DH;
  ea.dc = dc;
  ea.flags = eflags;
  hipFuncSetAttribute((const void*)enc_seq,
                      hipFuncAttributeMaxDynamicSharedMemorySize, LDS_ENC);
  enc_seq<<<dim3(64), 256, LDS_ENC, stream>>>(ea);

  // --- eq = enc_out @ wi ; eo2 = enc_out @ wo_st (both row-major) ---
  gemm128h<<<dim3(8,25),256,0,stream>>>(enc_out, DH, wiT_h, DH, zb, eq_h, DH, DH, 3200, DH);
  gemm128h<<<dim3(8,25),256,0,stream>>>(enc_out, DH, wo_h, 2048, zb, eo2_h, DH, DH, 3200, DH);

  // --- decoder (persistent, 224 WGs, 2 exposed hops/step) ---
  DA da;
  da.wo = wo_h; da.wdh = wdh_h; da.w3c = w3c;
  da.eq = eq_h; da.eo2 = eo2_h;
  da.pp = peproj;
  da.dh = dh; da.dc = dc;
  da.ct = ct; da.wdd = wdd;
  da.hdec = hdec;
  da.flags = dflags;
  hipFuncSetAttribute((const void*)dec_seq,
                      hipFuncAttributeMaxDynamicSharedMemorySize, LDS_TOT);
  dec_seq<<<dim3(224), 256, LDS_TOT, stream>>>(da);

  // --- generator + log-softmax ---
  gemm128<<<dim3(GVP/128,25),256,0,stream>>>(hdec, DH, genw_h, DH, genb, out, GV, DH, 3136, GV, NB);
  lsm<<<3136,256,0,stream>>>(out);
}